// Round 1
// baseline (1007.010 us; speedup 1.0000x reference)
//
#include <hip/hip_runtime.h>
#include <math.h>

#define NN 50000
#define NE 500000
#define HIDS 128
#define MCOLS 896   // q(256) k(256) v(256) skip(128)
#define NLAYERS 3

// ---------- helpers ----------
static __device__ __forceinline__ float bflo(unsigned u) { return __uint_as_float(u << 16); }
static __device__ __forceinline__ float bfhi(unsigned u) { return __uint_as_float(u & 0xffff0000u); }
static __device__ __forceinline__ unsigned short f2bf(float f) {
    unsigned u = __float_as_uint(f);
    u += 0x7fffu + ((u >> 16) & 1u);   // RNE
    return (unsigned short)(u >> 16);
}
static __device__ __forceinline__ float wred32(float v) {
    v += __shfl_xor(v, 1, 32);
    v += __shfl_xor(v, 2, 32);
    v += __shfl_xor(v, 4, 32);
    v += __shfl_xor(v, 8, 32);
    v += __shfl_xor(v, 16, 32);
    return v;
}
static __device__ __forceinline__ float wred64(float v) {
    v += __shfl_xor(v, 1, 64);
    v += __shfl_xor(v, 2, 64);
    v += __shfl_xor(v, 4, 64);
    v += __shfl_xor(v, 8, 64);
    v += __shfl_xor(v, 16, 64);
    v += __shfl_xor(v, 32, 64);
    return v;
}

// ---------- CSR build ----------
__global__ __launch_bounds__(256) void eatb_count(const int* __restrict__ tgt, int* __restrict__ cnt) {
    int e = blockIdx.x * 256 + threadIdx.x;
    if (e < NE) atomicAdd(&cnt[tgt[e]], 1);
}

__global__ __launch_bounds__(256) void eatb_blocksum(const int* __restrict__ cnt, int* __restrict__ bsums) {
    __shared__ int sm[256];
    int i = blockIdx.x * 256 + threadIdx.x;
    sm[threadIdx.x] = (i < NN) ? cnt[i] : 0;
    __syncthreads();
    for (int off = 128; off > 0; off >>= 1) {
        if (threadIdx.x < off) sm[threadIdx.x] += sm[threadIdx.x + off];
        __syncthreads();
    }
    if (threadIdx.x == 0) bsums[blockIdx.x] = sm[0];
}

__global__ __launch_bounds__(256) void eatb_scanb(int* __restrict__ bsums, int nb) {
    __shared__ int sm[256];
    int t = threadIdx.x;
    int v = (t < nb) ? bsums[t] : 0;
    sm[t] = v;
    __syncthreads();
    for (int off = 1; off < 256; off <<= 1) {
        int x = (t >= off) ? sm[t - off] : 0;
        __syncthreads();
        sm[t] += x;
        __syncthreads();
    }
    if (t < nb) bsums[t] = sm[t] - v;   // exclusive
}

__global__ __launch_bounds__(256) void eatb_rowstart(const int* __restrict__ cnt, const int* __restrict__ bsums,
                                                     int* __restrict__ row_start) {
    __shared__ int sm[256];
    int t = threadIdx.x;
    int i = blockIdx.x * 256 + t;
    int v = (i < NN) ? cnt[i] : 0;
    sm[t] = v;
    __syncthreads();
    for (int off = 1; off < 256; off <<= 1) {
        int x = (t >= off) ? sm[t - off] : 0;
        __syncthreads();
        sm[t] += x;
        __syncthreads();
    }
    int excl = sm[t] - v + bsums[blockIdx.x];
    if (i < NN) row_start[i] = excl;
    if (i == NN - 1) row_start[NN] = excl + v;
}

__global__ __launch_bounds__(256) void eatb_scatter(const int* __restrict__ src, const int* __restrict__ tgt,
                                                    const float* __restrict__ ea, const int* __restrict__ row_start,
                                                    int* __restrict__ cursor, int2* __restrict__ csr) {
    int e = blockIdx.x * 256 + threadIdx.x;
    if (e >= NE) return;
    int t = tgt[e];
    int pos = atomicAdd(&cursor[t], 1);
    int2 val;
    val.x = src[e];
    val.y = __float_as_int(ea[e]);
    csr[row_start[t] + pos] = val;
}

// ---------- pack concatenated weights ----------
__global__ __launch_bounds__(256) void eatb_packw(const float* __restrict__ Wq, const float* __restrict__ Wk,
                                                  const float* __restrict__ Wv, const float* __restrict__ Ws,
                                                  const float* __restrict__ bq, const float* __restrict__ bk,
                                                  const float* __restrict__ bv, const float* __restrict__ bs,
                                                  float* __restrict__ Wcat, float* __restrict__ bcat) {
    int idx = blockIdx.x * 256 + threadIdx.x;
    const int WTOT = NLAYERS * HIDS * MCOLS;
    if (idx < WTOT) {
        int l = idx / (HIDS * MCOLS);
        int rem = idx % (HIDS * MCOLS);
        int k = rem / MCOLS, c = rem % MCOLS;
        float v;
        if (c < 256)      v = Wq[(l * HIDS + k) * 256 + c];
        else if (c < 512) v = Wk[(l * HIDS + k) * 256 + c - 256];
        else if (c < 768) v = Wv[(l * HIDS + k) * 256 + c - 512];
        else              v = Ws[(l * HIDS + k) * 128 + c - 768];
        Wcat[idx] = v;
    } else {
        int i2 = idx - WTOT;
        if (i2 < NLAYERS * MCOLS) {
            int l = i2 / MCOLS, c = i2 % MCOLS;
            float v;
            if (c < 256)      v = bq[l * 256 + c];
            else if (c < 512) v = bk[l * 256 + c - 256];
            else if (c < 768) v = bv[l * 256 + c - 512];
            else              v = bs[l * 128 + c - 768];
            bcat[i2] = v;
        }
    }
}

// ---------- input layernorm (wave per node, 2 elems/lane) ----------
__global__ __launch_bounds__(256) void eatb_ln_in(const float* __restrict__ x, const float* __restrict__ g,
                                                  const float* __restrict__ b, float* __restrict__ xout) {
    int wid = threadIdx.x >> 6, lane = threadIdx.x & 63;
    int n = blockIdx.x * 4 + wid;
    if (n >= NN) return;
    float2 v = *(const float2*)(x + (size_t)n * HIDS + 2 * lane);
    float mu = wred64(v.x + v.y) * (1.f / 128.f);
    float cx = v.x - mu, cy = v.y - mu;
    float var = wred64(cx * cx + cy * cy) * (1.f / 128.f);
    float r = rsqrtf(var + 1e-5f);
    float2 g2 = *(const float2*)(g + 2 * lane);
    float2 b2 = *(const float2*)(b + 2 * lane);
    float2 o;
    o.x = cx * r * g2.x + b2.x;
    o.y = cy * r * g2.y + b2.y;
    *(float2*)(xout + (size_t)n * HIDS + 2 * lane) = o;
}

// ---------- fp32 GEMM: [NN,128] @ [128,896] + bias, fused routing epilogue ----------
// qbuf fp32 [NN,256]; kvpack bf16 [NN][64 lanes][8] (k pair4 + v pair4 per lane, head=lane/32);
// skipbuf fp32 [NN,128]
__global__ __launch_bounds__(256) void eatb_gemm(const float* __restrict__ A, const float* __restrict__ B,
                                                 const float* __restrict__ bias, float* __restrict__ qbuf,
                                                 unsigned short* __restrict__ kvpack, float* __restrict__ skipbuf) {
    __shared__ float As[64 * 128];   // [row][k]
    __shared__ float Bs[128 * 64];   // [k][col]
    int tid = threadIdx.x;
    int r0 = blockIdx.x * 64;
    int c0 = blockIdx.y * 64;

    {   // load A tile (coalesced float4, natural layout)
        int row = tid >> 5;
        int k4 = (tid & 31) << 2;
        #pragma unroll
        for (int p = 0; p < 8; ++p) {
            int r = row + p * 8;
            int gr = r0 + r;
            float4 a = make_float4(0.f, 0.f, 0.f, 0.f);
            if (gr < NN) a = *(const float4*)(A + (size_t)gr * HIDS + k4);
            *(float4*)(As + r * 128 + k4) = a;
        }
    }
    {   // load B tile
        int k = tid >> 4;
        int c4 = (tid & 15) << 2;
        #pragma unroll
        for (int p = 0; p < 8; ++p) {
            int kk = k + p * 16;
            float4 bvv = *(const float4*)(B + (size_t)kk * MCOLS + c0 + c4);
            *(float4*)(Bs + kk * 64 + c4) = bvv;
        }
    }
    __syncthreads();

    int tc = (tid & 15) << 2;   // 0..60 col offset
    int tr = (tid >> 4) << 2;   // 0..60 row offset
    float acc[4][4] = {};
    #pragma unroll 2
    for (int kk4 = 0; kk4 < 128; kk4 += 4) {
        float4 a[4], bb[4];
        #pragma unroll
        for (int i = 0; i < 4; ++i) a[i] = *(const float4*)(As + (tr + i) * 128 + kk4);
        #pragma unroll
        for (int j = 0; j < 4; ++j) bb[j] = *(const float4*)(Bs + (kk4 + j) * 64 + tc);
        #pragma unroll
        for (int i = 0; i < 4; ++i) {
            acc[i][0] = fmaf(a[i].x, bb[0].x, acc[i][0]);
            acc[i][1] = fmaf(a[i].x, bb[0].y, acc[i][1]);
            acc[i][2] = fmaf(a[i].x, bb[0].z, acc[i][2]);
            acc[i][3] = fmaf(a[i].x, bb[0].w, acc[i][3]);
            acc[i][0] = fmaf(a[i].y, bb[1].x, acc[i][0]);
            acc[i][1] = fmaf(a[i].y, bb[1].y, acc[i][1]);
            acc[i][2] = fmaf(a[i].y, bb[1].z, acc[i][2]);
            acc[i][3] = fmaf(a[i].y, bb[1].w, acc[i][3]);
            acc[i][0] = fmaf(a[i].z, bb[2].x, acc[i][0]);
            acc[i][1] = fmaf(a[i].z, bb[2].y, acc[i][1]);
            acc[i][2] = fmaf(a[i].z, bb[2].z, acc[i][2]);
            acc[i][3] = fmaf(a[i].z, bb[2].w, acc[i][3]);
            acc[i][0] = fmaf(a[i].w, bb[3].x, acc[i][0]);
            acc[i][1] = fmaf(a[i].w, bb[3].y, acc[i][1]);
            acc[i][2] = fmaf(a[i].w, bb[3].z, acc[i][2]);
            acc[i][3] = fmaf(a[i].w, bb[3].w, acc[i][3]);
        }
    }

    // epilogue: add bias, route by column region (tile-uniform: c0 multiple of 64)
    int c = c0 + tc;
    float4 bias4 = *(const float4*)(bias + c);
    float bvals[4] = {bias4.x, bias4.y, bias4.z, bias4.w};
    #pragma unroll
    for (int i = 0; i < 4; ++i) {
        int r = r0 + tr + i;
        if (r >= NN) break;
        float vals[4];
        #pragma unroll
        for (int j = 0; j < 4; ++j) vals[j] = acc[i][j] + bvals[j];
        if (c < 256) {
            *(float4*)(qbuf + (size_t)r * 256 + c) = make_float4(vals[0], vals[1], vals[2], vals[3]);
        } else if (c < 768) {
            int u = c - 256;          // 0..511
            int part = u >> 7;        // 0:k0 1:k1 2:v0 3:v1
            int h = part & 1;
            int isv = part >> 1;
            int d = u & 127;
            int t = h * 32 + (d >> 2);
            int jb = isv * 4;
            unsigned lo = (unsigned)f2bf(vals[0]) | ((unsigned)f2bf(vals[1]) << 16);
            unsigned hi = (unsigned)f2bf(vals[2]) | ((unsigned)f2bf(vals[3]) << 16);
            *(uint2*)(kvpack + (((size_t)r * 64 + t) * 8 + jb)) = make_uint2(lo, hi);
        } else {
            *(float4*)(skipbuf + (size_t)r * 128 + (c - 768)) = make_float4(vals[0], vals[1], vals[2], vals[3]);
        }
    }
}

// ---------- fused attention + epilogue: one wave per target node ----------
// lanes 0..31 = head0, 32..63 = head1; lane handles dims 4*(lane&31)..+3 of its head
__global__ __launch_bounds__(256) void eatb_attn(const float* __restrict__ qbuf,
                                                 const unsigned short* __restrict__ kvpack,
                                                 const float* __restrict__ skipbuf,
                                                 const int2* __restrict__ csr, const int* __restrict__ row_start,
                                                 const float* __restrict__ Wel, const float* __restrict__ g,
                                                 const float* __restrict__ beta, const float* __restrict__ xcur,
                                                 float* __restrict__ dst) {
    int wid = threadIdx.x >> 6;
    int lane = threadIdx.x & 63;
    int n = blockIdx.x * 4 + wid;
    if (n >= NN) return;
    int half = lane >> 5;
    int d0 = (lane & 31) << 2;

    float4 q4 = *(const float4*)(qbuf + (size_t)n * 256 + half * 128 + d0);
    float4 we4 = *(const float4*)(Wel + half * 128 + d0);
    float qwe = wred32(q4.x * we4.x + q4.y * we4.y + q4.z * we4.z + q4.w * we4.w);

    float m = -INFINITY, s = 0.f, sea = 0.f;
    float a0 = 0.f, a1 = 0.f, a2 = 0.f, a3 = 0.f;
    const float rs = 0.08838834764831845f;   // 1/sqrt(128)
    int beg = row_start[n], end = row_start[n + 1];
    for (int i = beg; i < end; ++i) {
        int2 se = csr[i];
        int sidx = se.x;
        float ea = __int_as_float(se.y);
        uint4 kv = *(const uint4*)(kvpack + (((size_t)sidx << 6) + lane) * 8);
        float k0 = bflo(kv.x), k1 = bfhi(kv.x), k2 = bflo(kv.y), k3 = bfhi(kv.y);
        float v0 = bflo(kv.z), v1 = bfhi(kv.z), v2 = bflo(kv.w), v3 = bfhi(kv.w);
        float p = q4.x * k0 + q4.y * k1 + q4.z * k2 + q4.w * k3;
        p = wred32(p);
        float alpha = (p + ea * qwe) * rs;
        float nm = fmaxf(m, alpha);
        float esc = __expf(m - nm);
        float w = __expf(alpha - nm);
        s = s * esc + w;
        sea = sea * esc + w * ea;
        a0 = a0 * esc + w * v0;
        a1 = a1 * esc + w * v1;
        a2 = a2 * esc + w * v2;
        a3 = a3 * esc + w * v3;
        m = nm;
    }
    float inv = (s > 0.f) ? 1.f / s : 1.f;
    float sw = sea * inv;
    float o0 = a0 * inv + sw * we4.x;
    float o1 = a1 * inv + sw * we4.y;
    float o2 = a2 * inv + sw * we4.z;
    float o3 = a3 * inv + sw * we4.w;
    // head mean (exchange halves)
    o0 = 0.5f * (o0 + __shfl_xor(o0, 32, 64));
    o1 = 0.5f * (o1 + __shfl_xor(o1, 32, 64));
    o2 = 0.5f * (o2 + __shfl_xor(o2, 32, 64));
    o3 = 0.5f * (o3 + __shfl_xor(o3, 32, 64));
    // + skip, ELU, residual, LN
    float4 sk = *(const float4*)(skipbuf + (size_t)n * 128 + d0);
    float4 xr = *(const float4*)(xcur + (size_t)n * 128 + d0);
    float y0 = o0 + sk.x, y1 = o1 + sk.y, y2 = o2 + sk.z, y3 = o3 + sk.w;
    y0 = (y0 > 0.f) ? y0 : expm1f(y0);
    y1 = (y1 > 0.f) ? y1 : expm1f(y1);
    y2 = (y2 > 0.f) ? y2 : expm1f(y2);
    y3 = (y3 > 0.f) ? y3 : expm1f(y3);
    float p0 = xr.x + y0, p1 = xr.y + y1, p2 = xr.z + y2, p3 = xr.w + y3;
    float mu = wred32(p0 + p1 + p2 + p3) * (1.f / 128.f);
    float c0 = p0 - mu, c1 = p1 - mu, c2 = p2 - mu, c3 = p3 - mu;
    float var = wred32(c0 * c0 + c1 * c1 + c2 * c2 + c3 * c3) * (1.f / 128.f);
    float r = rsqrtf(var + 1e-5f);
    if (lane < 32) {
        float4 g4 = *(const float4*)(g + d0);
        float4 b4 = *(const float4*)(beta + d0);
        float4 o;
        o.x = c0 * r * g4.x + b4.x;
        o.y = c1 * r * g4.y + b4.y;
        o.z = c2 * r * g4.z + b4.z;
        o.w = c3 * r * g4.w + b4.w;
        *(float4*)(dst + (size_t)n * 128 + d0) = o;
    }
}

// ---------- launch ----------
extern "C" void kernel_launch(void* const* d_in, const int* in_sizes, int n_in,
                              void* d_out, int out_size, void* d_ws, size_t ws_size,
                              hipStream_t stream) {
    const float* x       = (const float*)d_in[0];
    const int*   ei      = (const int*)d_in[1];
    const float* eattr   = (const float*)d_in[2];
    const float* ln_in_g = (const float*)d_in[3];
    const float* ln_in_b = (const float*)d_in[4];
    const float* Wq = (const float*)d_in[5];
    const float* bq = (const float*)d_in[6];
    const float* Wk = (const float*)d_in[7];
    const float* bk = (const float*)d_in[8];
    const float* Wv = (const float*)d_in[9];
    const float* bv = (const float*)d_in[10];
    const float* We = (const float*)d_in[11];
    const float* Ws = (const float*)d_in[12];
    const float* bs = (const float*)d_in[13];
    const float* ln_g = (const float*)d_in[14];
    const float* ln_b = (const float*)d_in[15];
    float* out = (float*)d_out;

    char* p = (char*)d_ws;
    auto carve = [&](size_t bytes) {
        char* r = p;
        p += (bytes + 255) & ~(size_t)255;
        return (void*)r;
    };
    int*  cursor    = (int*)carve((size_t)NN * 4);
    int*  row_start = (int*)carve((size_t)(NN + 1) * 4);
    int*  bsums     = (int*)carve(1024);
    int2* csr       = (int2*)carve((size_t)NE * 8);
    float* Wcat     = (float*)carve((size_t)NLAYERS * HIDS * MCOLS * 4);
    float* bcat     = (float*)carve((size_t)NLAYERS * MCOLS * 4);
    float* xcur     = (float*)carve((size_t)NN * HIDS * 4);
    float* qbuf     = (float*)carve((size_t)NN * 256 * 4);
    unsigned short* kvpack = (unsigned short*)carve((size_t)NN * 512 * 2);
    float* skipbuf  = (float*)carve((size_t)NN * HIDS * 4);

    const int NB_N = (NN + 255) / 256;       // 196
    const int NB_E = (NE + 255) / 256;       // 1954
    const int NODE_BLOCKS = (NN + 3) / 4;    // 12500

    // CSR build (edge_index layout: src = ei[0:E], tgt = ei[E:2E])
    hipMemsetAsync(cursor, 0, (size_t)NN * 4, stream);
    eatb_count<<<NB_E, 256, 0, stream>>>(ei + NE, cursor);
    eatb_blocksum<<<NB_N, 256, 0, stream>>>(cursor, bsums);
    eatb_scanb<<<1, 256, 0, stream>>>(bsums, NB_N);
    eatb_rowstart<<<NB_N, 256, 0, stream>>>(cursor, bsums, row_start);
    hipMemsetAsync(cursor, 0, (size_t)NN * 4, stream);
    eatb_scatter<<<NB_E, 256, 0, stream>>>(ei, ei + NE, eattr, row_start, cursor, csr);

    // pack weights
    {
        int tot = NLAYERS * HIDS * MCOLS + NLAYERS * MCOLS;
        eatb_packw<<<(tot + 255) / 256, 256, 0, stream>>>(Wq, Wk, Wv, Ws, bq, bk, bv, bs, Wcat, bcat);
    }

    // input layernorm
    eatb_ln_in<<<NODE_BLOCKS, 256, 0, stream>>>(x, ln_in_g, ln_in_b, xcur);

    // layers
    dim3 ggrid((NN + 63) / 64, MCOLS / 64);
    for (int l = 0; l < NLAYERS; ++l) {
        eatb_gemm<<<ggrid, 256, 0, stream>>>(xcur, Wcat + (size_t)l * HIDS * MCOLS, bcat + (size_t)l * MCOLS,
                                             qbuf, kvpack, skipbuf);
        float* dst = (l == NLAYERS - 1) ? out : xcur;
        eatb_attn<<<NODE_BLOCKS, 256, 0, stream>>>(qbuf, kvpack, skipbuf, csr, row_start,
                                                   We + (size_t)l * 256, ln_g + (size_t)l * 128,
                                                   ln_b + (size_t)l * 128, xcur, dst);
    }
    (void)in_sizes; (void)n_in; (void)out_size; (void)ws_size;
}

// Round 2
// 638.365 us; speedup vs baseline: 1.5775x; 1.5775x over previous
//
#include <hip/hip_runtime.h>
#include <math.h>

#define NN 50000
#define NE 500000
#define HIDS 128
#define MCOLS 896   // q(256) k(256) v(256) skip(128)
#define NLAYERS 3

typedef __attribute__((ext_vector_type(8))) short short8;
typedef __attribute__((ext_vector_type(4))) float floatx4;

#define STR 152     // LDS A/B row stride in shorts: 128+24 -> 304 B (16B-aligned, 2-way-free frag reads)

// ---------- helpers ----------
static __device__ __forceinline__ float bflo(unsigned u) { return __uint_as_float(u << 16); }
static __device__ __forceinline__ float bfhi(unsigned u) { return __uint_as_float(u & 0xffff0000u); }
static __device__ __forceinline__ unsigned short f2bf(float f) {
    unsigned u = __float_as_uint(f);
    u += 0x7fffu + ((u >> 16) & 1u);   // RNE
    return (unsigned short)(u >> 16);
}
static __device__ __forceinline__ float wred32(float v) {
    v += __shfl_xor(v, 1, 32);
    v += __shfl_xor(v, 2, 32);
    v += __shfl_xor(v, 4, 32);
    v += __shfl_xor(v, 8, 32);
    v += __shfl_xor(v, 16, 32);
    return v;
}
static __device__ __forceinline__ float wred64(float v) {
    v += __shfl_xor(v, 1, 64);
    v += __shfl_xor(v, 2, 64);
    v += __shfl_xor(v, 4, 64);
    v += __shfl_xor(v, 8, 64);
    v += __shfl_xor(v, 16, 64);
    v += __shfl_xor(v, 32, 64);
    return v;
}

// ---------- CSR build ----------
__global__ __launch_bounds__(256) void eatb_count(const int* __restrict__ tgt, int* __restrict__ cnt) {
    int e = blockIdx.x * 256 + threadIdx.x;
    if (e < NE) atomicAdd(&cnt[tgt[e]], 1);
}

__global__ __launch_bounds__(256) void eatb_blocksum(const int* __restrict__ cnt, int* __restrict__ bsums) {
    __shared__ int sm[256];
    int i = blockIdx.x * 256 + threadIdx.x;
    sm[threadIdx.x] = (i < NN) ? cnt[i] : 0;
    __syncthreads();
    for (int off = 128; off > 0; off >>= 1) {
        if (threadIdx.x < off) sm[threadIdx.x] += sm[threadIdx.x + off];
        __syncthreads();
    }
    if (threadIdx.x == 0) bsums[blockIdx.x] = sm[0];
}

__global__ __launch_bounds__(256) void eatb_scanb(int* __restrict__ bsums, int nb) {
    __shared__ int sm[256];
    int t = threadIdx.x;
    int v = (t < nb) ? bsums[t] : 0;
    sm[t] = v;
    __syncthreads();
    for (int off = 1; off < 256; off <<= 1) {
        int x = (t >= off) ? sm[t - off] : 0;
        __syncthreads();
        sm[t] += x;
        __syncthreads();
    }
    if (t < nb) bsums[t] = sm[t] - v;   // exclusive
}

__global__ __launch_bounds__(256) void eatb_rowstart(const int* __restrict__ cnt, const int* __restrict__ bsums,
                                                     int* __restrict__ row_start) {
    __shared__ int sm[256];
    int t = threadIdx.x;
    int i = blockIdx.x * 256 + t;
    int v = (i < NN) ? cnt[i] : 0;
    sm[t] = v;
    __syncthreads();
    for (int off = 1; off < 256; off <<= 1) {
        int x = (t >= off) ? sm[t - off] : 0;
        __syncthreads();
        sm[t] += x;
        __syncthreads();
    }
    int excl = sm[t] - v + bsums[blockIdx.x];
    if (i < NN) row_start[i] = excl;
    if (i == NN - 1) row_start[NN] = excl + v;
}

__global__ __launch_bounds__(256) void eatb_scatter(const int* __restrict__ src, const int* __restrict__ tgt,
                                                    const float* __restrict__ ea, const int* __restrict__ row_start,
                                                    int* __restrict__ cursor, int2* __restrict__ csr) {
    int e = blockIdx.x * 256 + threadIdx.x;
    if (e >= NE) return;
    int t = tgt[e];
    int pos = atomicAdd(&cursor[t], 1);
    int2 val;
    val.x = src[e];
    val.y = __float_as_int(ea[e]);
    csr[row_start[t] + pos] = val;
}

// ---------- pack transposed bf16 weights: WcatT[l][c=0..895][k=0..127] ----------
__global__ __launch_bounds__(256) void eatb_packw(const float* __restrict__ Wq, const float* __restrict__ Wk,
                                                  const float* __restrict__ Wv, const float* __restrict__ Ws,
                                                  const float* __restrict__ bq, const float* __restrict__ bk,
                                                  const float* __restrict__ bv, const float* __restrict__ bs,
                                                  unsigned short* __restrict__ Wt, float* __restrict__ bcat) {
    int idx = blockIdx.x * 256 + threadIdx.x;
    const int WTOT = NLAYERS * MCOLS * HIDS;
    if (idx < WTOT) {
        int l = idx / (MCOLS * HIDS);
        int rem = idx % (MCOLS * HIDS);
        int c = rem / HIDS, k = rem % HIDS;
        float v;
        if (c < 256)      v = Wq[(l * HIDS + k) * 256 + c];
        else if (c < 512) v = Wk[(l * HIDS + k) * 256 + c - 256];
        else if (c < 768) v = Wv[(l * HIDS + k) * 256 + c - 512];
        else              v = Ws[(l * HIDS + k) * 128 + c - 768];
        Wt[idx] = f2bf(v);
    } else {
        int i2 = idx - WTOT;
        if (i2 < NLAYERS * MCOLS) {
            int l = i2 / MCOLS, c = i2 % MCOLS;
            float v;
            if (c < 256)      v = bq[l * 256 + c];
            else if (c < 512) v = bk[l * 256 + c - 256];
            else if (c < 768) v = bv[l * 256 + c - 512];
            else              v = bs[l * 128 + c - 768];
            bcat[i2] = v;
        }
    }
}

// ---------- input layernorm (wave per node) -> fp32 xcur + bf16 xb ----------
__global__ __launch_bounds__(256) void eatb_ln_in(const float* __restrict__ x, const float* __restrict__ g,
                                                  const float* __restrict__ b, float* __restrict__ xout,
                                                  unsigned short* __restrict__ xb) {
    int wid = threadIdx.x >> 6, lane = threadIdx.x & 63;
    int n = blockIdx.x * 4 + wid;
    if (n >= NN) return;
    float2 v = *(const float2*)(x + (size_t)n * HIDS + 2 * lane);
    float mu = wred64(v.x + v.y) * (1.f / 128.f);
    float cx = v.x - mu, cy = v.y - mu;
    float var = wred64(cx * cx + cy * cy) * (1.f / 128.f);
    float r = rsqrtf(var + 1e-5f);
    float2 g2 = *(const float2*)(g + 2 * lane);
    float2 b2 = *(const float2*)(b + 2 * lane);
    float2 o;
    o.x = cx * r * g2.x + b2.x;
    o.y = cy * r * g2.y + b2.y;
    *(float2*)(xout + (size_t)n * HIDS + 2 * lane) = o;
    unsigned pk = (unsigned)f2bf(o.x) | ((unsigned)f2bf(o.y) << 16);
    *(unsigned*)(xb + (size_t)n * HIDS + 2 * lane) = pk;
}

// ---------- bf16 MFMA GEMM: [NN,128]bf16 @ [128,896]bf16 + bias, fused routing ----------
// qpack bf16 [NN][256] row-major; kvpack bf16 [NN][64 lanes][8]; skipbuf fp32 [NN][128]
__global__ __launch_bounds__(256, 2) void eatb_gemm(const unsigned short* __restrict__ xb,
                                                    const unsigned short* __restrict__ Wt,
                                                    const float* __restrict__ bias,
                                                    unsigned short* __restrict__ qpack,
                                                    unsigned short* __restrict__ kvpack,
                                                    float* __restrict__ skipbuf) {
    __shared__ __align__(16) char smem[2 * 128 * STR * 2];   // 77824 B; C-stage (128*129*4=66048) unions in
    short* As = (short*)smem;            // [128][STR]
    short* Bs = As + 128 * STR;          // [128][STR]
    float* Cs = (float*)smem;            // [128][129]

    int tid = threadIdx.x;
    int r0 = blockIdx.x * 128;
    int c0 = blockIdx.y * 128;

    {   // stage A,B tiles: thread t loads 16B chunks; row=(t>>4)+16p, chunk=(t&15)*8 shorts
        int row = tid >> 4, ch = (tid & 15) * 8;
        #pragma unroll
        for (int p = 0; p < 8; ++p) {
            int r = row + p * 16;
            int gr = r0 + r;
            uint4 v = make_uint4(0, 0, 0, 0);
            if (gr < NN) v = *(const uint4*)(xb + (size_t)gr * HIDS + ch);
            *(uint4*)(As + r * STR + ch) = v;
        }
        #pragma unroll
        for (int p = 0; p < 8; ++p) {
            int r = row + p * 16;
            uint4 v = *(const uint4*)(Wt + (size_t)(c0 + r) * HIDS + ch);
            *(uint4*)(Bs + r * STR + ch) = v;
        }
    }
    __syncthreads();

    int wid = tid >> 6, lane = tid & 63;
    int fr = lane & 15;
    int kq = (lane >> 4) * 8;
    floatx4 acc[2][8] = {};
    #pragma unroll
    for (int ks = 0; ks < 4; ++ks) {
        int kof = ks * 32 + kq;
        short8 af0 = *(const short8*)(As + (wid * 32 + fr) * STR + kof);
        short8 af1 = *(const short8*)(As + (wid * 32 + 16 + fr) * STR + kof);
        short8 bf[8];
        #pragma unroll
        for (int n = 0; n < 8; ++n) bf[n] = *(const short8*)(Bs + (n * 16 + fr) * STR + kof);
        #pragma unroll
        for (int n = 0; n < 8; ++n) {
            acc[0][n] = __builtin_amdgcn_mfma_f32_16x16x32_bf16(af0, bf[n], acc[0][n], 0, 0, 0);
            acc[1][n] = __builtin_amdgcn_mfma_f32_16x16x32_bf16(af1, bf[n], acc[1][n], 0, 0, 0);
        }
    }
    __syncthreads();   // A/B reads done; reuse LDS for C staging
    #pragma unroll
    for (int mi = 0; mi < 2; ++mi)
        #pragma unroll
        for (int ni = 0; ni < 8; ++ni)
            #pragma unroll
            for (int rg = 0; rg < 4; ++rg) {
                int rr = wid * 32 + mi * 16 + (lane >> 4) * 4 + rg;
                int cc = ni * 16 + fr;
                Cs[rr * 129 + cc] = acc[mi][ni][rg];
            }
    __syncthreads();

    // routed stores: thread t: cols 4*(t&31).., rows (t>>5)+8p
    int cl = (tid & 31) * 4;
    int C = c0 + cl;
    float4 b4 = *(const float4*)(bias + C);
    for (int p = 0; p < 16; ++p) {
        int rr = (tid >> 5) + 8 * p;
        int gr = r0 + rr;
        if (gr >= NN) break;
        float v0 = Cs[rr * 129 + cl] + b4.x;
        float v1 = Cs[rr * 129 + cl + 1] + b4.y;
        float v2 = Cs[rr * 129 + cl + 2] + b4.z;
        float v3 = Cs[rr * 129 + cl + 3] + b4.w;
        if (C < 256) {
            ushort4 o;
            o.x = f2bf(v0); o.y = f2bf(v1); o.z = f2bf(v2); o.w = f2bf(v3);
            *(ushort4*)(qpack + (size_t)gr * 256 + C) = o;
        } else if (C < 768) {
            int u = C - 256;
            int part = u >> 7;
            int h = part & 1, isv = part >> 1;
            int m = (u & 127) >> 2;
            ushort4 o;
            o.x = f2bf(v0); o.y = f2bf(v1); o.z = f2bf(v2); o.w = f2bf(v3);
            *(ushort4*)(kvpack + (size_t)gr * 512 + (h * 32 + m) * 8 + isv * 4) = o;
        } else {
            *(float4*)(skipbuf + (size_t)gr * 128 + (C - 768)) = make_float4(v0, v1, v2, v3);
        }
    }
}

// ---------- fused attention + epilogue: one wave per target node ----------
__global__ __launch_bounds__(256) void eatb_attn(const unsigned short* __restrict__ qpack,
                                                 const unsigned short* __restrict__ kvpack,
                                                 const float* __restrict__ skipbuf,
                                                 const int2* __restrict__ csr, const int* __restrict__ row_start,
                                                 const float* __restrict__ Wel, const float* __restrict__ g,
                                                 const float* __restrict__ beta, const float* __restrict__ xcur,
                                                 float* __restrict__ dst, unsigned short* __restrict__ xbout) {
    int wid = threadIdx.x >> 6;
    int lane = threadIdx.x & 63;
    int n = blockIdx.x * 4 + wid;
    if (n >= NN) return;
    int half = lane >> 5;
    int d0 = (lane & 31) << 2;

    ushort4 qp = *(const ushort4*)(qpack + (size_t)n * 256 + half * 128 + d0);
    float4 q4 = make_float4(bflo(qp.x), bflo(qp.y), bflo(qp.z), bflo(qp.w));
    float4 we4 = *(const float4*)(Wel + half * 128 + d0);
    float qwe = wred32(q4.x * we4.x + q4.y * we4.y + q4.z * we4.z + q4.w * we4.w);

    float m = -INFINITY, s = 0.f, sea = 0.f;
    float a0 = 0.f, a1 = 0.f, a2 = 0.f, a3 = 0.f;
    const float rs = 0.08838834764831845f;   // 1/sqrt(128)
    int beg = row_start[n], end = row_start[n + 1];
    for (int i = beg; i < end; ++i) {
        int2 se = csr[i];
        int sidx = se.x;
        float ea = __int_as_float(se.y);
        uint4 kv = *(const uint4*)(kvpack + (((size_t)sidx << 6) + lane) * 8);
        float k0 = bflo(kv.x), k1 = bfhi(kv.x), k2 = bflo(kv.y), k3 = bfhi(kv.y);
        float v0 = bflo(kv.z), v1 = bfhi(kv.z), v2 = bflo(kv.w), v3 = bfhi(kv.w);
        float p = q4.x * k0 + q4.y * k1 + q4.z * k2 + q4.w * k3;
        p = wred32(p);
        float alpha = (p + ea * qwe) * rs;
        float nm = fmaxf(m, alpha);
        float esc = __expf(m - nm);
        float w = __expf(alpha - nm);
        s = s * esc + w;
        sea = sea * esc + w * ea;
        a0 = a0 * esc + w * v0;
        a1 = a1 * esc + w * v1;
        a2 = a2 * esc + w * v2;
        a3 = a3 * esc + w * v3;
        m = nm;
    }
    float inv = (s > 0.f) ? 1.f / s : 1.f;
    float sw = sea * inv;
    float o0 = a0 * inv + sw * we4.x;
    float o1 = a1 * inv + sw * we4.y;
    float o2 = a2 * inv + sw * we4.z;
    float o3 = a3 * inv + sw * we4.w;
    o0 = 0.5f * (o0 + __shfl_xor(o0, 32, 64));
    o1 = 0.5f * (o1 + __shfl_xor(o1, 32, 64));
    o2 = 0.5f * (o2 + __shfl_xor(o2, 32, 64));
    o3 = 0.5f * (o3 + __shfl_xor(o3, 32, 64));
    float4 sk = *(const float4*)(skipbuf + (size_t)n * 128 + d0);
    float4 xr = *(const float4*)(xcur + (size_t)n * 128 + d0);
    float y0 = o0 + sk.x, y1 = o1 + sk.y, y2 = o2 + sk.z, y3 = o3 + sk.w;
    y0 = (y0 > 0.f) ? y0 : expm1f(y0);
    y1 = (y1 > 0.f) ? y1 : expm1f(y1);
    y2 = (y2 > 0.f) ? y2 : expm1f(y2);
    y3 = (y3 > 0.f) ? y3 : expm1f(y3);
    float p0 = xr.x + y0, p1 = xr.y + y1, p2 = xr.z + y2, p3 = xr.w + y3;
    float mu = wred32(p0 + p1 + p2 + p3) * (1.f / 128.f);
    float c0 = p0 - mu, c1 = p1 - mu, c2 = p2 - mu, c3 = p3 - mu;
    float var = wred32(c0 * c0 + c1 * c1 + c2 * c2 + c3 * c3) * (1.f / 128.f);
    float r = rsqrtf(var + 1e-5f);
    if (lane < 32) {
        float4 g4 = *(const float4*)(g + d0);
        float4 b4 = *(const float4*)(beta + d0);
        float4 o;
        o.x = c0 * r * g4.x + b4.x;
        o.y = c1 * r * g4.y + b4.y;
        o.z = c2 * r * g4.z + b4.z;
        o.w = c3 * r * g4.w + b4.w;
        *(float4*)(dst + (size_t)n * 128 + d0) = o;
        if (xbout) {
            ushort4 ob;
            ob.x = f2bf(o.x); ob.y = f2bf(o.y); ob.z = f2bf(o.z); ob.w = f2bf(o.w);
            *(ushort4*)(xbout + (size_t)n * 128 + d0) = ob;
        }
    }
}

// ---------- launch ----------
extern "C" void kernel_launch(void* const* d_in, const int* in_sizes, int n_in,
                              void* d_out, int out_size, void* d_ws, size_t ws_size,
                              hipStream_t stream) {
    const float* x       = (const float*)d_in[0];
    const int*   ei      = (const int*)d_in[1];
    const float* eattr   = (const float*)d_in[2];
    const float* ln_in_g = (const float*)d_in[3];
    const float* ln_in_b = (const float*)d_in[4];
    const float* Wq = (const float*)d_in[5];
    const float* bq = (const float*)d_in[6];
    const float* Wk = (const float*)d_in[7];
    const float* bk = (const float*)d_in[8];
    const float* Wv = (const float*)d_in[9];
    const float* bv = (const float*)d_in[10];
    const float* We = (const float*)d_in[11];
    const float* Ws = (const float*)d_in[12];
    const float* bs = (const float*)d_in[13];
    const float* ln_g = (const float*)d_in[14];
    const float* ln_b = (const float*)d_in[15];
    float* out = (float*)d_out;

    char* p = (char*)d_ws;
    auto carve = [&](size_t bytes) {
        char* r = p;
        p += (bytes + 255) & ~(size_t)255;
        return (void*)r;
    };
    int*  cursor    = (int*)carve((size_t)NN * 4);
    int*  row_start = (int*)carve((size_t)(NN + 1) * 4);
    int*  bsums     = (int*)carve(1024);
    int2* csr       = (int2*)carve((size_t)NE * 8);
    unsigned short* WcatT = (unsigned short*)carve((size_t)NLAYERS * MCOLS * HIDS * 2);
    float* bcat     = (float*)carve((size_t)NLAYERS * MCOLS * 4);
    float* xcur     = (float*)carve((size_t)NN * HIDS * 4);
    unsigned short* qpack  = (unsigned short*)carve((size_t)NN * 256 * 2);
    unsigned short* kvpack = (unsigned short*)carve((size_t)NN * 512 * 2);
    float* skipbuf  = (float*)carve((size_t)NN * HIDS * 4);
    unsigned short* xb = (unsigned short*)carve((size_t)NN * HIDS * 2);

    const int NB_N = (NN + 255) / 256;       // 196
    const int NB_E = (NE + 255) / 256;       // 1954
    const int NODE_BLOCKS = (NN + 3) / 4;    // 12500

    // CSR build (edge_index layout: src = ei[0:E], tgt = ei[E:2E])
    hipMemsetAsync(cursor, 0, (size_t)NN * 4, stream);
    eatb_count<<<NB_E, 256, 0, stream>>>(ei + NE, cursor);
    eatb_blocksum<<<NB_N, 256, 0, stream>>>(cursor, bsums);
    eatb_scanb<<<1, 256, 0, stream>>>(bsums, NB_N);
    eatb_rowstart<<<NB_N, 256, 0, stream>>>(cursor, bsums, row_start);
    hipMemsetAsync(cursor, 0, (size_t)NN * 4, stream);
    eatb_scatter<<<NB_E, 256, 0, stream>>>(ei, ei + NE, eattr, row_start, cursor, csr);

    // pack weights (transposed bf16) + biases
    {
        int tot = NLAYERS * MCOLS * HIDS + NLAYERS * MCOLS;
        eatb_packw<<<(tot + 255) / 256, 256, 0, stream>>>(Wq, Wk, Wv, Ws, bq, bk, bv, bs, WcatT, bcat);
    }

    // input layernorm -> xcur (fp32) + xb (bf16)
    eatb_ln_in<<<NODE_BLOCKS, 256, 0, stream>>>(x, ln_in_g, ln_in_b, xcur, xb);

    // layers
    dim3 ggrid((NN + 127) / 128, MCOLS / 128);   // 391 x 7
    for (int l = 0; l < NLAYERS; ++l) {
        eatb_gemm<<<ggrid, 256, 0, stream>>>(xb, WcatT + (size_t)l * MCOLS * HIDS, bcat + (size_t)l * MCOLS,
                                             qpack, kvpack, skipbuf);
        float* dst = (l == NLAYERS - 1) ? out : xcur;
        unsigned short* xbo = (l == NLAYERS - 1) ? nullptr : xb;
        eatb_attn<<<NODE_BLOCKS, 256, 0, stream>>>(qpack, kvpack, skipbuf, csr, row_start,
                                                   We + (size_t)l * 256, ln_g + (size_t)l * 128,
                                                   ln_b + (size_t)l * 128, xcur, dst, xbo);
    }
    (void)in_sizes; (void)n_in; (void)out_size; (void)ws_size;
}

// Round 3
// 611.247 us; speedup vs baseline: 1.6475x; 1.0444x over previous
//
#include <hip/hip_runtime.h>
#include <math.h>

#define NN 50000
#define NE 500000
#define HIDS 128
#define MCOLS 896   // q(256) k(256) v(256) skip(128)
#define NLAYERS 3

typedef __attribute__((ext_vector_type(8))) short short8;
typedef __attribute__((ext_vector_type(4))) float floatx4;

#define STR 152     // LDS A/B row stride in shorts: 128+24 -> 304 B (16B-aligned, 2-way-free frag reads)

// ---------- helpers ----------
static __device__ __forceinline__ float bflo(unsigned u) { return __uint_as_float(u << 16); }
static __device__ __forceinline__ float bfhi(unsigned u) { return __uint_as_float(u & 0xffff0000u); }
static __device__ __forceinline__ unsigned short f2bf(float f) {
    unsigned u = __float_as_uint(f);
    u += 0x7fffu + ((u >> 16) & 1u);   // RNE
    return (unsigned short)(u >> 16);
}
static __device__ __forceinline__ float wred16(float v) {
    v += __shfl_xor(v, 1, 64);
    v += __shfl_xor(v, 2, 64);
    v += __shfl_xor(v, 4, 64);
    v += __shfl_xor(v, 8, 64);
    return v;
}
static __device__ __forceinline__ float wred64(float v) {
    v += __shfl_xor(v, 1, 64);
    v += __shfl_xor(v, 2, 64);
    v += __shfl_xor(v, 4, 64);
    v += __shfl_xor(v, 8, 64);
    v += __shfl_xor(v, 16, 64);
    v += __shfl_xor(v, 32, 64);
    return v;
}

// ---------- CSR build ----------
__global__ __launch_bounds__(256) void eatb_count(const int* __restrict__ tgt, int* __restrict__ cnt) {
    int e = blockIdx.x * 256 + threadIdx.x;
    if (e < NE) atomicAdd(&cnt[tgt[e]], 1);
}

__global__ __launch_bounds__(256) void eatb_blocksum(const int* __restrict__ cnt, int* __restrict__ bsums) {
    __shared__ int sm[256];
    int i = blockIdx.x * 256 + threadIdx.x;
    sm[threadIdx.x] = (i < NN) ? cnt[i] : 0;
    __syncthreads();
    for (int off = 128; off > 0; off >>= 1) {
        if (threadIdx.x < off) sm[threadIdx.x] += sm[threadIdx.x + off];
        __syncthreads();
    }
    if (threadIdx.x == 0) bsums[blockIdx.x] = sm[0];
}

__global__ __launch_bounds__(256) void eatb_scanb(int* __restrict__ bsums, int nb) {
    __shared__ int sm[256];
    int t = threadIdx.x;
    int v = (t < nb) ? bsums[t] : 0;
    sm[t] = v;
    __syncthreads();
    for (int off = 1; off < 256; off <<= 1) {
        int x = (t >= off) ? sm[t - off] : 0;
        __syncthreads();
        sm[t] += x;
        __syncthreads();
    }
    if (t < nb) bsums[t] = sm[t] - v;   // exclusive
}

__global__ __launch_bounds__(256) void eatb_rowstart(const int* __restrict__ cnt, const int* __restrict__ bsums,
                                                     int* __restrict__ row_start) {
    __shared__ int sm[256];
    int t = threadIdx.x;
    int i = blockIdx.x * 256 + t;
    int v = (i < NN) ? cnt[i] : 0;
    sm[t] = v;
    __syncthreads();
    for (int off = 1; off < 256; off <<= 1) {
        int x = (t >= off) ? sm[t - off] : 0;
        __syncthreads();
        sm[t] += x;
        __syncthreads();
    }
    int excl = sm[t] - v + bsums[blockIdx.x];
    if (i < NN) row_start[i] = excl;
    if (i == NN - 1) row_start[NN] = excl + v;
}

__global__ __launch_bounds__(256) void eatb_scatter(const int* __restrict__ src, const int* __restrict__ tgt,
                                                    const float* __restrict__ ea, const int* __restrict__ row_start,
                                                    int* __restrict__ cursor, int2* __restrict__ csr) {
    int e = blockIdx.x * 256 + threadIdx.x;
    if (e >= NE) return;
    int t = tgt[e];
    int pos = atomicAdd(&cursor[t], 1);
    int2 val;
    val.x = src[e];
    val.y = __float_as_int(ea[e]);
    csr[row_start[t] + pos] = val;
}

// ---------- pack transposed bf16 weights: WcatT[l][c=0..895][k=0..127] ----------
__global__ __launch_bounds__(256) void eatb_packw(const float* __restrict__ Wq, const float* __restrict__ Wk,
                                                  const float* __restrict__ Wv, const float* __restrict__ Ws,
                                                  const float* __restrict__ bq, const float* __restrict__ bk,
                                                  const float* __restrict__ bv, const float* __restrict__ bs,
                                                  unsigned short* __restrict__ Wt, float* __restrict__ bcat) {
    int idx = blockIdx.x * 256 + threadIdx.x;
    const int WTOT = NLAYERS * MCOLS * HIDS;
    if (idx < WTOT) {
        int l = idx / (MCOLS * HIDS);
        int rem = idx % (MCOLS * HIDS);
        int c = rem / HIDS, k = rem % HIDS;
        float v;
        if (c < 256)      v = Wq[(l * HIDS + k) * 256 + c];
        else if (c < 512) v = Wk[(l * HIDS + k) * 256 + c - 256];
        else if (c < 768) v = Wv[(l * HIDS + k) * 256 + c - 512];
        else              v = Ws[(l * HIDS + k) * 128 + c - 768];
        Wt[idx] = f2bf(v);
    } else {
        int i2 = idx - WTOT;
        if (i2 < NLAYERS * MCOLS) {
            int l = i2 / MCOLS, c = i2 % MCOLS;
            float v;
            if (c < 256)      v = bq[l * 256 + c];
            else if (c < 512) v = bk[l * 256 + c - 256];
            else if (c < 768) v = bv[l * 256 + c - 512];
            else              v = bs[l * 128 + c - 768];
            bcat[i2] = v;
        }
    }
}

// ---------- input layernorm (wave per node) -> fp32 xcur + bf16 xb ----------
__global__ __launch_bounds__(256) void eatb_ln_in(const float* __restrict__ x, const float* __restrict__ g,
                                                  const float* __restrict__ b, float* __restrict__ xout,
                                                  unsigned short* __restrict__ xb) {
    int wid = threadIdx.x >> 6, lane = threadIdx.x & 63;
    int n = blockIdx.x * 4 + wid;
    if (n >= NN) return;
    float2 v = *(const float2*)(x + (size_t)n * HIDS + 2 * lane);
    float mu = wred64(v.x + v.y) * (1.f / 128.f);
    float cx = v.x - mu, cy = v.y - mu;
    float var = wred64(cx * cx + cy * cy) * (1.f / 128.f);
    float r = rsqrtf(var + 1e-5f);
    float2 g2 = *(const float2*)(g + 2 * lane);
    float2 b2 = *(const float2*)(b + 2 * lane);
    float2 o;
    o.x = cx * r * g2.x + b2.x;
    o.y = cy * r * g2.y + b2.y;
    *(float2*)(xout + (size_t)n * HIDS + 2 * lane) = o;
    unsigned pk = (unsigned)f2bf(o.x) | ((unsigned)f2bf(o.y) << 16);
    *(unsigned*)(xb + (size_t)n * HIDS + 2 * lane) = pk;
}

// ---------- bf16 MFMA GEMM: [NN,128]bf16 @ [128,896]bf16 + bias, fused routing ----------
// qpack bf16 [NN][256] row-major
// kvpack bf16 [NN][head:2][sl:16][k 8 | v 8]  (32 B per (head,sl) granule, 1 KB per node)
// skipbuf fp32 [NN][128]
__global__ __launch_bounds__(256, 2) void eatb_gemm(const unsigned short* __restrict__ xb,
                                                    const unsigned short* __restrict__ Wt,
                                                    const float* __restrict__ bias,
                                                    unsigned short* __restrict__ qpack,
                                                    unsigned short* __restrict__ kvpack,
                                                    float* __restrict__ skipbuf) {
    __shared__ __align__(16) char smem[2 * 128 * STR * 2];   // 77824 B; C-stage (128*129*4=66048) unions in
    short* As = (short*)smem;            // [128][STR]
    short* Bs = As + 128 * STR;          // [128][STR]
    float* Cs = (float*)smem;            // [128][129]

    int tid = threadIdx.x;
    int r0 = blockIdx.x * 128;
    int c0 = blockIdx.y * 128;

    {   // stage A,B tiles: thread t loads 16B chunks; row=(t>>4)+16p, chunk=(t&15)*8 shorts
        int row = tid >> 4, ch = (tid & 15) * 8;
        #pragma unroll
        for (int p = 0; p < 8; ++p) {
            int r = row + p * 16;
            int gr = r0 + r;
            uint4 v = make_uint4(0, 0, 0, 0);
            if (gr < NN) v = *(const uint4*)(xb + (size_t)gr * HIDS + ch);
            *(uint4*)(As + r * STR + ch) = v;
        }
        #pragma unroll
        for (int p = 0; p < 8; ++p) {
            int r = row + p * 16;
            uint4 v = *(const uint4*)(Wt + (size_t)(c0 + r) * HIDS + ch);
            *(uint4*)(Bs + r * STR + ch) = v;
        }
    }
    __syncthreads();

    int wid = tid >> 6, lane = tid & 63;
    int fr = lane & 15;
    int kq = (lane >> 4) * 8;
    floatx4 acc[2][8] = {};
    #pragma unroll
    for (int ks = 0; ks < 4; ++ks) {
        int kof = ks * 32 + kq;
        short8 af0 = *(const short8*)(As + (wid * 32 + fr) * STR + kof);
        short8 af1 = *(const short8*)(As + (wid * 32 + 16 + fr) * STR + kof);
        short8 bf[8];
        #pragma unroll
        for (int n = 0; n < 8; ++n) bf[n] = *(const short8*)(Bs + (n * 16 + fr) * STR + kof);
        #pragma unroll
        for (int n = 0; n < 8; ++n) {
            acc[0][n] = __builtin_amdgcn_mfma_f32_16x16x32_bf16(af0, bf[n], acc[0][n], 0, 0, 0);
            acc[1][n] = __builtin_amdgcn_mfma_f32_16x16x32_bf16(af1, bf[n], acc[1][n], 0, 0, 0);
        }
    }
    __syncthreads();   // A/B reads done; reuse LDS for C staging
    #pragma unroll
    for (int mi = 0; mi < 2; ++mi)
        #pragma unroll
        for (int ni = 0; ni < 8; ++ni)
            #pragma unroll
            for (int rg = 0; rg < 4; ++rg) {
                int rr = wid * 32 + mi * 16 + (lane >> 4) * 4 + rg;
                int cc = ni * 16 + fr;
                Cs[rr * 129 + cc] = acc[mi][ni][rg];
            }
    __syncthreads();

    // routed stores: thread t: cols 4*(t&31).., rows (t>>5)+8p
    int cl = (tid & 31) * 4;
    int C = c0 + cl;
    float4 b4 = *(const float4*)(bias + C);
    for (int p = 0; p < 16; ++p) {
        int rr = (tid >> 5) + 8 * p;
        int gr = r0 + rr;
        if (gr >= NN) break;
        float v0 = Cs[rr * 129 + cl] + b4.x;
        float v1 = Cs[rr * 129 + cl + 1] + b4.y;
        float v2 = Cs[rr * 129 + cl + 2] + b4.z;
        float v3 = Cs[rr * 129 + cl + 3] + b4.w;
        if (C < 256) {
            ushort4 o;
            o.x = f2bf(v0); o.y = f2bf(v1); o.z = f2bf(v2); o.w = f2bf(v3);
            *(ushort4*)(qpack + (size_t)gr * 256 + C) = o;
        } else if (C < 768) {
            int u = C - 256;
            int part = u >> 7;        // 0:k h0, 1:k h1, 2:v h0, 3:v h1
            int h = part & 1, isv = part >> 1;
            int d0 = u & 127;         // dim base (multiple of 4)
            ushort4 o;
            o.x = f2bf(v0); o.y = f2bf(v1); o.z = f2bf(v2); o.w = f2bf(v3);
            size_t off = (size_t)gr * 512 + ((h * 16 + (d0 >> 3)) * 16) + isv * 8 + (d0 & 7);
            *(ushort4*)(kvpack + off) = o;
        } else {
            *(float4*)(skipbuf + (size_t)gr * 128 + (C - 768)) = make_float4(v0, v1, v2, v3);
        }
    }
}

// ---------- fused attention + epilogue: one wave per target node ----------
// lane map: slot = lane>>5 (edge slot), h = (lane>>4)&1, sl = lane&15 (dims sl*8..sl*8+7)
__global__ __launch_bounds__(256) void eatb_attn(const unsigned short* __restrict__ qpack,
                                                 const unsigned short* __restrict__ kvpack,
                                                 const float* __restrict__ skipbuf,
                                                 const int2* __restrict__ csr, const int* __restrict__ row_start,
                                                 const float* __restrict__ Wel, const float* __restrict__ g,
                                                 const float* __restrict__ beta, const float* __restrict__ xcur,
                                                 float* __restrict__ dst, unsigned short* __restrict__ xbout) {
    int wid = threadIdx.x >> 6;
    int lane = threadIdx.x & 63;
    int n = blockIdx.x * 4 + wid;
    if (n >= NN) return;
    int slot = lane >> 5;
    int h = (lane >> 4) & 1;
    int sl = lane & 15;
    int dbase = sl * 8;

    // q fragment (8 dims of head h), fp32
    uint4 qw = *(const uint4*)(qpack + (size_t)n * 256 + h * 128 + dbase);
    float q0 = bflo(qw.x), q1 = bfhi(qw.x), q2 = bflo(qw.y), q3 = bfhi(qw.y);
    float q4 = bflo(qw.z), q5 = bfhi(qw.z), q6 = bflo(qw.w), q7 = bfhi(qw.w);
    const float* wep = Wel + h * 128 + dbase;
    float4 wea = *(const float4*)wep;
    float4 web = *(const float4*)(wep + 4);
    float qwe = wred16(q0 * wea.x + q1 * wea.y + q2 * wea.z + q3 * wea.w +
                       q4 * web.x + q5 * web.y + q6 * web.z + q7 * web.w);

    float m = -INFINITY, s = 0.f, sea = 0.f;
    float a0 = 0.f, a1 = 0.f, a2 = 0.f, a3 = 0.f, a4 = 0.f, a5 = 0.f, a6 = 0.f, a7 = 0.f;
    const float rs = 0.08838834764831845f;   // 1/sqrt(128)
    int beg = row_start[n], end = row_start[n + 1];
    int nit = (end - beg + 1) >> 1;
    for (int it = 0; it < nit; ++it) {
        int e0 = beg + 2 * it;
        int2 se0 = csr[e0];
        int2 se1 = csr[e0 + 1];          // may read 8B past last row's edges; in-ws, masked below
        int e = e0 + slot;
        bool valid = e < end;
        int2 se = slot ? se1 : se0;
        int sidx = valid ? se.x : 0;
        float ea = __int_as_float(se.y);
        const unsigned short* kvb = kvpack + ((size_t)sidx << 9) + ((h * 16 + sl) << 4);
        uint4 kq = *(const uint4*)kvb;
        uint4 vq = *(const uint4*)(kvb + 8);
        float p = q0 * bflo(kq.x) + q1 * bfhi(kq.x) + q2 * bflo(kq.y) + q3 * bfhi(kq.y) +
                  q4 * bflo(kq.z) + q5 * bfhi(kq.z) + q6 * bflo(kq.w) + q7 * bfhi(kq.w);
        p = wred16(p);
        float alpha = valid ? (p + ea * qwe) * rs : -INFINITY;
        float nm = fmaxf(m, alpha);
        float esc = __expf(fminf(m - nm, 0.f));      // fmin kills -inf-(-inf) NaN
        float w = valid ? __expf(alpha - nm) : 0.f;
        s = s * esc + w;
        sea = sea * esc + w * ea;
        a0 = a0 * esc + w * bflo(vq.x);
        a1 = a1 * esc + w * bfhi(vq.x);
        a2 = a2 * esc + w * bflo(vq.y);
        a3 = a3 * esc + w * bfhi(vq.y);
        a4 = a4 * esc + w * bflo(vq.z);
        a5 = a5 * esc + w * bfhi(vq.z);
        a6 = a6 * esc + w * bflo(vq.w);
        a7 = a7 * esc + w * bfhi(vq.w);
        m = nm;
    }

    // merge the two edge slots (lane ^ 32)
    {
        float om = __shfl_xor(m, 32, 64);
        float M = fmaxf(m, om);
        float es = __expf(fminf(m - M, 0.f));
        float eo = __expf(fminf(om - M, 0.f));
        float os = __shfl_xor(s, 32, 64);
        float osea = __shfl_xor(sea, 32, 64);
        s = s * es + os * eo;
        sea = sea * es + osea * eo;
        a0 = a0 * es + __shfl_xor(a0, 32, 64) * eo;
        a1 = a1 * es + __shfl_xor(a1, 32, 64) * eo;
        a2 = a2 * es + __shfl_xor(a2, 32, 64) * eo;
        a3 = a3 * es + __shfl_xor(a3, 32, 64) * eo;
        a4 = a4 * es + __shfl_xor(a4, 32, 64) * eo;
        a5 = a5 * es + __shfl_xor(a5, 32, 64) * eo;
        a6 = a6 * es + __shfl_xor(a6, 32, 64) * eo;
        a7 = a7 * es + __shfl_xor(a7, 32, 64) * eo;
    }

    float inv = (s > 0.f) ? 1.f / s : 1.f;
    float sw = sea * inv;
    float o0 = a0 * inv + sw * wea.x;
    float o1 = a1 * inv + sw * wea.y;
    float o2 = a2 * inv + sw * wea.z;
    float o3 = a3 * inv + sw * wea.w;
    float o4 = a4 * inv + sw * web.x;
    float o5 = a5 * inv + sw * web.y;
    float o6 = a6 * inv + sw * web.z;
    float o7 = a7 * inv + sw * web.w;
    // head mean (h <-> h^1 is lane ^ 16)
    o0 = 0.5f * (o0 + __shfl_xor(o0, 16, 64));
    o1 = 0.5f * (o1 + __shfl_xor(o1, 16, 64));
    o2 = 0.5f * (o2 + __shfl_xor(o2, 16, 64));
    o3 = 0.5f * (o3 + __shfl_xor(o3, 16, 64));
    o4 = 0.5f * (o4 + __shfl_xor(o4, 16, 64));
    o5 = 0.5f * (o5 + __shfl_xor(o5, 16, 64));
    o6 = 0.5f * (o6 + __shfl_xor(o6, 16, 64));
    o7 = 0.5f * (o7 + __shfl_xor(o7, 16, 64));

    // + skip, ELU, residual, LN (dims dbase..dbase+7; 4x redundant across (slot,h))
    const float* skp = skipbuf + (size_t)n * 128 + dbase;
    const float* xrp = xcur + (size_t)n * 128 + dbase;
    float4 ska = *(const float4*)skp, skb = *(const float4*)(skp + 4);
    float4 xra = *(const float4*)xrp, xrb = *(const float4*)(xrp + 4);
    float y0 = o0 + ska.x, y1 = o1 + ska.y, y2 = o2 + ska.z, y3 = o3 + ska.w;
    float y4 = o4 + skb.x, y5 = o5 + skb.y, y6 = o6 + skb.z, y7 = o7 + skb.w;
    y0 = (y0 > 0.f) ? y0 : expm1f(y0);
    y1 = (y1 > 0.f) ? y1 : expm1f(y1);
    y2 = (y2 > 0.f) ? y2 : expm1f(y2);
    y3 = (y3 > 0.f) ? y3 : expm1f(y3);
    y4 = (y4 > 0.f) ? y4 : expm1f(y4);
    y5 = (y5 > 0.f) ? y5 : expm1f(y5);
    y6 = (y6 > 0.f) ? y6 : expm1f(y6);
    y7 = (y7 > 0.f) ? y7 : expm1f(y7);
    float p0 = xra.x + y0, p1 = xra.y + y1, p2 = xra.z + y2, p3 = xra.w + y3;
    float p4 = xrb.x + y4, p5 = xrb.y + y5, p6 = xrb.z + y6, p7 = xrb.w + y7;
    float mu = wred16(p0 + p1 + p2 + p3 + p4 + p5 + p6 + p7) * (1.f / 128.f);
    float c0 = p0 - mu, c1 = p1 - mu, c2 = p2 - mu, c3 = p3 - mu;
    float c4 = p4 - mu, c5 = p5 - mu, c6 = p6 - mu, c7 = p7 - mu;
    float var = wred16(c0 * c0 + c1 * c1 + c2 * c2 + c3 * c3 +
                       c4 * c4 + c5 * c5 + c6 * c6 + c7 * c7) * (1.f / 128.f);
    float r = rsqrtf(var + 1e-5f);
    if (lane < 16) {
        const float* gp = g + dbase;
        const float* bp = beta + dbase;
        float4 ga = *(const float4*)gp, gb = *(const float4*)(gp + 4);
        float4 ba = *(const float4*)bp, bb = *(const float4*)(bp + 4);
        float4 oa, ob;
        oa.x = c0 * r * ga.x + ba.x; oa.y = c1 * r * ga.y + ba.y;
        oa.z = c2 * r * ga.z + ba.z; oa.w = c3 * r * ga.w + ba.w;
        ob.x = c4 * r * gb.x + bb.x; ob.y = c5 * r * gb.y + bb.y;
        ob.z = c6 * r * gb.z + bb.z; ob.w = c7 * r * gb.w + bb.w;
        float* dp = dst + (size_t)n * 128 + dbase;
        *(float4*)dp = oa;
        *(float4*)(dp + 4) = ob;
        if (xbout) {
            uint4 pk;
            pk.x = (unsigned)f2bf(oa.x) | ((unsigned)f2bf(oa.y) << 16);
            pk.y = (unsigned)f2bf(oa.z) | ((unsigned)f2bf(oa.w) << 16);
            pk.z = (unsigned)f2bf(ob.x) | ((unsigned)f2bf(ob.y) << 16);
            pk.w = (unsigned)f2bf(ob.z) | ((unsigned)f2bf(ob.w) << 16);
            *(uint4*)(xbout + (size_t)n * 128 + dbase) = pk;
        }
    }
}

// ---------- launch ----------
extern "C" void kernel_launch(void* const* d_in, const int* in_sizes, int n_in,
                              void* d_out, int out_size, void* d_ws, size_t ws_size,
                              hipStream_t stream) {
    const float* x       = (const float*)d_in[0];
    const int*   ei      = (const int*)d_in[1];
    const float* eattr   = (const float*)d_in[2];
    const float* ln_in_g = (const float*)d_in[3];
    const float* ln_in_b = (const float*)d_in[4];
    const float* Wq = (const float*)d_in[5];
    const float* bq = (const float*)d_in[6];
    const float* Wk = (const float*)d_in[7];
    const float* bk = (const float*)d_in[8];
    const float* Wv = (const float*)d_in[9];
    const float* bv = (const float*)d_in[10];
    const float* We = (const float*)d_in[11];
    const float* Ws = (const float*)d_in[12];
    const float* bs = (const float*)d_in[13];
    const float* ln_g = (const float*)d_in[14];
    const float* ln_b = (const float*)d_in[15];
    float* out = (float*)d_out;

    char* p = (char*)d_ws;
    auto carve = [&](size_t bytes) {
        char* r = p;
        p += (bytes + 255) & ~(size_t)255;
        return (void*)r;
    };
    int*  cursor    = (int*)carve((size_t)NN * 4);
    int*  row_start = (int*)carve((size_t)(NN + 1) * 4);
    int*  bsums     = (int*)carve(1024);
    int2* csr       = (int2*)carve((size_t)NE * 8);
    unsigned short* WcatT = (unsigned short*)carve((size_t)NLAYERS * MCOLS * HIDS * 2);
    float* bcat     = (float*)carve((size_t)NLAYERS * MCOLS * 4);
    float* xcur     = (float*)carve((size_t)NN * HIDS * 4);
    unsigned short* qpack  = (unsigned short*)carve((size_t)NN * 256 * 2);
    unsigned short* kvpack = (unsigned short*)carve((size_t)NN * 512 * 2);
    float* skipbuf  = (float*)carve((size_t)NN * HIDS * 4);
    unsigned short* xb = (unsigned short*)carve((size_t)NN * HIDS * 2);

    const int NB_N = (NN + 255) / 256;       // 196
    const int NB_E = (NE + 255) / 256;       // 1954
    const int NODE_BLOCKS = (NN + 3) / 4;    // 12500

    // CSR build (edge_index layout: src = ei[0:E], tgt = ei[E:2E])
    hipMemsetAsync(cursor, 0, (size_t)NN * 4, stream);
    eatb_count<<<NB_E, 256, 0, stream>>>(ei + NE, cursor);
    eatb_blocksum<<<NB_N, 256, 0, stream>>>(cursor, bsums);
    eatb_scanb<<<1, 256, 0, stream>>>(bsums, NB_N);
    eatb_rowstart<<<NB_N, 256, 0, stream>>>(cursor, bsums, row_start);
    hipMemsetAsync(cursor, 0, (size_t)NN * 4, stream);
    eatb_scatter<<<NB_E, 256, 0, stream>>>(ei, ei + NE, eattr, row_start, cursor, csr);

    // pack weights (transposed bf16) + biases
    {
        int tot = NLAYERS * MCOLS * HIDS + NLAYERS * MCOLS;
        eatb_packw<<<(tot + 255) / 256, 256, 0, stream>>>(Wq, Wk, Wv, Ws, bq, bk, bv, bs, WcatT, bcat);
    }

    // input layernorm -> xcur (fp32) + xb (bf16)
    eatb_ln_in<<<NODE_BLOCKS, 256, 0, stream>>>(x, ln_in_g, ln_in_b, xcur, xb);

    // layers
    dim3 ggrid((NN + 127) / 128, MCOLS / 128);   // 391 x 7
    for (int l = 0; l < NLAYERS; ++l) {
        eatb_gemm<<<ggrid, 256, 0, stream>>>(xb, WcatT + (size_t)l * MCOLS * HIDS, bcat + (size_t)l * MCOLS,
                                             qpack, kvpack, skipbuf);
        float* dst = (l == NLAYERS - 1) ? out : xcur;
        unsigned short* xbo = (l == NLAYERS - 1) ? nullptr : xb;
        eatb_attn<<<NODE_BLOCKS, 256, 0, stream>>>(qpack, kvpack, skipbuf, csr, row_start,
                                                   We + (size_t)l * 256, ln_g + (size_t)l * 128,
                                                   ln_b + (size_t)l * 128, xcur, dst, xbo);
    }
    (void)in_sizes; (void)n_in; (void)out_size; (void)ws_size;
}

// Round 4
// 610.708 us; speedup vs baseline: 1.6489x; 1.0009x over previous
//
#include <hip/hip_runtime.h>
#include <math.h>

#define NN 50000
#define NE 500000
#define HIDS 128
#define MCOLS 896   // q(256) k(256) v(256) skip(128)
#define NLAYERS 3

typedef __attribute__((ext_vector_type(8))) short short8;
typedef __attribute__((ext_vector_type(4))) float floatx4;

#define STR 152     // LDS A/B row stride in shorts: 128+24 -> 304 B (16B-aligned, 2-way-free frag reads)

// ---------- helpers ----------
static __device__ __forceinline__ float bflo(unsigned u) { return __uint_as_float(u << 16); }
static __device__ __forceinline__ float bfhi(unsigned u) { return __uint_as_float(u & 0xffff0000u); }
static __device__ __forceinline__ unsigned short f2bf(float f) {
    unsigned u = __float_as_uint(f);
    u += 0x7fffu + ((u >> 16) & 1u);   // RNE
    return (unsigned short)(u >> 16);
}
static __device__ __forceinline__ float wred16(float v) {
    v += __shfl_xor(v, 1, 64);
    v += __shfl_xor(v, 2, 64);
    v += __shfl_xor(v, 4, 64);
    v += __shfl_xor(v, 8, 64);
    return v;
}
static __device__ __forceinline__ float wred64(float v) {
    v += __shfl_xor(v, 1, 64);
    v += __shfl_xor(v, 2, 64);
    v += __shfl_xor(v, 4, 64);
    v += __shfl_xor(v, 8, 64);
    v += __shfl_xor(v, 16, 64);
    v += __shfl_xor(v, 32, 64);
    return v;
}

// ---------- CSR build ----------
__global__ __launch_bounds__(256) void eatb_count(const int* __restrict__ tgt, int* __restrict__ cnt) {
    int e = blockIdx.x * 256 + threadIdx.x;
    if (e < NE) atomicAdd(&cnt[tgt[e]], 1);
}

__global__ __launch_bounds__(256) void eatb_blocksum(const int* __restrict__ cnt, int* __restrict__ bsums) {
    __shared__ int sm[256];
    int i = blockIdx.x * 256 + threadIdx.x;
    sm[threadIdx.x] = (i < NN) ? cnt[i] : 0;
    __syncthreads();
    for (int off = 128; off > 0; off >>= 1) {
        if (threadIdx.x < off) sm[threadIdx.x] += sm[threadIdx.x + off];
        __syncthreads();
    }
    if (threadIdx.x == 0) bsums[blockIdx.x] = sm[0];
}

__global__ __launch_bounds__(256) void eatb_scanb(int* __restrict__ bsums, int nb) {
    __shared__ int sm[256];
    int t = threadIdx.x;
    int v = (t < nb) ? bsums[t] : 0;
    sm[t] = v;
    __syncthreads();
    for (int off = 1; off < 256; off <<= 1) {
        int x = (t >= off) ? sm[t - off] : 0;
        __syncthreads();
        sm[t] += x;
        __syncthreads();
    }
    if (t < nb) bsums[t] = sm[t] - v;   // exclusive
}

__global__ __launch_bounds__(256) void eatb_rowstart(const int* __restrict__ cnt, const int* __restrict__ bsums,
                                                     int* __restrict__ row_start) {
    __shared__ int sm[256];
    int t = threadIdx.x;
    int i = blockIdx.x * 256 + t;
    int v = (i < NN) ? cnt[i] : 0;
    sm[t] = v;
    __syncthreads();
    for (int off = 1; off < 256; off <<= 1) {
        int x = (t >= off) ? sm[t - off] : 0;
        __syncthreads();
        sm[t] += x;
        __syncthreads();
    }
    int excl = sm[t] - v + bsums[blockIdx.x];
    if (i < NN) row_start[i] = excl;
    if (i == NN - 1) row_start[NN] = excl + v;
}

__global__ __launch_bounds__(256) void eatb_scatter(const int* __restrict__ src, const int* __restrict__ tgt,
                                                    const float* __restrict__ ea, const int* __restrict__ row_start,
                                                    int* __restrict__ cursor, int2* __restrict__ csr) {
    int e = blockIdx.x * 256 + threadIdx.x;
    if (e >= NE) return;
    int t = tgt[e];
    int pos = atomicAdd(&cursor[t], 1);
    int2 val;
    val.x = src[e];
    val.y = __float_as_int(ea[e]);
    csr[row_start[t] + pos] = val;
}

// ---------- pack transposed bf16 weights: WcatT[l][c=0..895][k=0..127] ----------
__global__ __launch_bounds__(256) void eatb_packw(const float* __restrict__ Wq, const float* __restrict__ Wk,
                                                  const float* __restrict__ Wv, const float* __restrict__ Ws,
                                                  const float* __restrict__ bq, const float* __restrict__ bk,
                                                  const float* __restrict__ bv, const float* __restrict__ bs,
                                                  unsigned short* __restrict__ Wt, float* __restrict__ bcat) {
    int idx = blockIdx.x * 256 + threadIdx.x;
    const int WTOT = NLAYERS * MCOLS * HIDS;
    if (idx < WTOT) {
        int l = idx / (MCOLS * HIDS);
        int rem = idx % (MCOLS * HIDS);
        int c = rem / HIDS, k = rem % HIDS;
        float v;
        if (c < 256)      v = Wq[(l * HIDS + k) * 256 + c];
        else if (c < 512) v = Wk[(l * HIDS + k) * 256 + c - 256];
        else if (c < 768) v = Wv[(l * HIDS + k) * 256 + c - 512];
        else              v = Ws[(l * HIDS + k) * 128 + c - 768];
        Wt[idx] = f2bf(v);
    } else {
        int i2 = idx - WTOT;
        if (i2 < NLAYERS * MCOLS) {
            int l = i2 / MCOLS, c = i2 % MCOLS;
            float v;
            if (c < 256)      v = bq[l * 256 + c];
            else if (c < 512) v = bk[l * 256 + c - 256];
            else if (c < 768) v = bv[l * 256 + c - 512];
            else              v = bs[l * 128 + c - 768];
            bcat[i2] = v;
        }
    }
}

// ---------- input layernorm (wave per node) -> fp32 xcur + bf16 xb ----------
__global__ __launch_bounds__(256) void eatb_ln_in(const float* __restrict__ x, const float* __restrict__ g,
                                                  const float* __restrict__ b, float* __restrict__ xout,
                                                  unsigned short* __restrict__ xb) {
    int wid = threadIdx.x >> 6, lane = threadIdx.x & 63;
    int n = blockIdx.x * 4 + wid;
    if (n >= NN) return;
    float2 v = *(const float2*)(x + (size_t)n * HIDS + 2 * lane);
    float mu = wred64(v.x + v.y) * (1.f / 128.f);
    float cx = v.x - mu, cy = v.y - mu;
    float var = wred64(cx * cx + cy * cy) * (1.f / 128.f);
    float r = rsqrtf(var + 1e-5f);
    float2 g2 = *(const float2*)(g + 2 * lane);
    float2 b2 = *(const float2*)(b + 2 * lane);
    float2 o;
    o.x = cx * r * g2.x + b2.x;
    o.y = cy * r * g2.y + b2.y;
    *(float2*)(xout + (size_t)n * HIDS + 2 * lane) = o;
    unsigned pk = (unsigned)f2bf(o.x) | ((unsigned)f2bf(o.y) << 16);
    *(unsigned*)(xb + (size_t)n * HIDS + 2 * lane) = pk;
}

// ---------- bf16 MFMA GEMM: [NN,128]bf16 @ [128,896]bf16 + bias, fused routing ----------
// qpack bf16 [NN][256] row-major
// kvpack bf16 [NN][head:2][sl:16][k 8 | v 8]  (32 B per (head,sl) granule, 1 KB per node)
// skipbuf fp32 [NN][128]
__global__ __launch_bounds__(256, 2) void eatb_gemm(const unsigned short* __restrict__ xb,
                                                    const unsigned short* __restrict__ Wt,
                                                    const float* __restrict__ bias,
                                                    unsigned short* __restrict__ qpack,
                                                    unsigned short* __restrict__ kvpack,
                                                    float* __restrict__ skipbuf) {
    __shared__ __align__(16) char smem[2 * 128 * STR * 2];   // 77824 B; C-stage (128*129*4=66048) unions in
    short* As = (short*)smem;            // [128][STR]
    short* Bs = As + 128 * STR;          // [128][STR]
    float* Cs = (float*)smem;            // [128][129]

    int tid = threadIdx.x;
    int r0 = blockIdx.x * 128;
    int c0 = blockIdx.y * 128;

    {   // stage A,B tiles: thread t loads 16B chunks; row=(t>>4)+16p, chunk=(t&15)*8 shorts
        int row = tid >> 4, ch = (tid & 15) * 8;
        #pragma unroll
        for (int p = 0; p < 8; ++p) {
            int r = row + p * 16;
            int gr = r0 + r;
            uint4 v = make_uint4(0, 0, 0, 0);
            if (gr < NN) v = *(const uint4*)(xb + (size_t)gr * HIDS + ch);
            *(uint4*)(As + r * STR + ch) = v;
        }
        #pragma unroll
        for (int p = 0; p < 8; ++p) {
            int r = row + p * 16;
            uint4 v = *(const uint4*)(Wt + (size_t)(c0 + r) * HIDS + ch);
            *(uint4*)(Bs + r * STR + ch) = v;
        }
    }
    __syncthreads();

    int wid = tid >> 6, lane = tid & 63;
    int fr = lane & 15;
    int kq = (lane >> 4) * 8;
    floatx4 acc[2][8] = {};
    #pragma unroll
    for (int ks = 0; ks < 4; ++ks) {
        int kof = ks * 32 + kq;
        short8 af0 = *(const short8*)(As + (wid * 32 + fr) * STR + kof);
        short8 af1 = *(const short8*)(As + (wid * 32 + 16 + fr) * STR + kof);
        short8 bf[8];
        #pragma unroll
        for (int n = 0; n < 8; ++n) bf[n] = *(const short8*)(Bs + (n * 16 + fr) * STR + kof);
        #pragma unroll
        for (int n = 0; n < 8; ++n) {
            acc[0][n] = __builtin_amdgcn_mfma_f32_16x16x32_bf16(af0, bf[n], acc[0][n], 0, 0, 0);
            acc[1][n] = __builtin_amdgcn_mfma_f32_16x16x32_bf16(af1, bf[n], acc[1][n], 0, 0, 0);
        }
    }
    __syncthreads();   // A/B reads done; reuse LDS for C staging
    #pragma unroll
    for (int mi = 0; mi < 2; ++mi)
        #pragma unroll
        for (int ni = 0; ni < 8; ++ni)
            #pragma unroll
            for (int rg = 0; rg < 4; ++rg) {
                int rr = wid * 32 + mi * 16 + (lane >> 4) * 4 + rg;
                int cc = ni * 16 + fr;
                Cs[rr * 129 + cc] = acc[mi][ni][rg];
            }
    __syncthreads();

    // routed stores: thread t: cols 4*(t&31).., rows (t>>5)+8p
    int cl = (tid & 31) * 4;
    int C = c0 + cl;
    float4 b4 = *(const float4*)(bias + C);
    for (int p = 0; p < 16; ++p) {
        int rr = (tid >> 5) + 8 * p;
        int gr = r0 + rr;
        if (gr >= NN) break;
        float v0 = Cs[rr * 129 + cl] + b4.x;
        float v1 = Cs[rr * 129 + cl + 1] + b4.y;
        float v2 = Cs[rr * 129 + cl + 2] + b4.z;
        float v3 = Cs[rr * 129 + cl + 3] + b4.w;
        if (C < 256) {
            ushort4 o;
            o.x = f2bf(v0); o.y = f2bf(v1); o.z = f2bf(v2); o.w = f2bf(v3);
            *(ushort4*)(qpack + (size_t)gr * 256 + C) = o;
        } else if (C < 768) {
            int u = C - 256;
            int part = u >> 7;        // 0:k h0, 1:k h1, 2:v h0, 3:v h1
            int h = part & 1, isv = part >> 1;
            int d0 = u & 127;         // dim base (multiple of 4)
            ushort4 o;
            o.x = f2bf(v0); o.y = f2bf(v1); o.z = f2bf(v2); o.w = f2bf(v3);
            size_t off = (size_t)gr * 512 + ((h * 16 + (d0 >> 3)) * 16) + isv * 8 + (d0 & 7);
            *(ushort4*)(kvpack + off) = o;
        } else {
            *(float4*)(skipbuf + (size_t)gr * 128 + (C - 768)) = make_float4(v0, v1, v2, v3);
        }
    }
}

// ---------- fused attention + epilogue: one wave per target node ----------
// lane map: slot = lane>>5 (edge slot), h = (lane>>4)&1, sl = lane&15 (dims sl*8..sl*8+7)
// No-max softmax: alpha is O(1)-scaled (|alpha| << 88 overflow bound), so w=exp(alpha)
// directly; removes the online-softmax serial rescale chain (a = a*esc + w*v -> single FMA).
__global__ __launch_bounds__(256) void eatb_attn(const unsigned short* __restrict__ qpack,
                                                 const unsigned short* __restrict__ kvpack,
                                                 const float* __restrict__ skipbuf,
                                                 const int2* __restrict__ csr, const int* __restrict__ row_start,
                                                 const float* __restrict__ Wel, const float* __restrict__ g,
                                                 const float* __restrict__ beta, const float* __restrict__ xcur,
                                                 float* __restrict__ dst, unsigned short* __restrict__ xbout) {
    int wid = threadIdx.x >> 6;
    int lane = threadIdx.x & 63;
    int n = blockIdx.x * 4 + wid;
    if (n >= NN) return;
    int slot = lane >> 5;
    int h = (lane >> 4) & 1;
    int sl = lane & 15;
    int dbase = sl * 8;

    // q fragment (8 dims of head h), fp32
    uint4 qw = *(const uint4*)(qpack + n * 256 + h * 128 + dbase);
    float q0 = bflo(qw.x), q1 = bfhi(qw.x), q2 = bflo(qw.y), q3 = bfhi(qw.y);
    float q4 = bflo(qw.z), q5 = bfhi(qw.z), q6 = bflo(qw.w), q7 = bfhi(qw.w);
    const float* wep = Wel + h * 128 + dbase;
    float4 wea = *(const float4*)wep;
    float4 web = *(const float4*)(wep + 4);
    float qwe = wred16(q0 * wea.x + q1 * wea.y + q2 * wea.z + q3 * wea.w +
                       q4 * web.x + q5 * web.y + q6 * web.z + q7 * web.w);

    float s = 0.f, sea = 0.f;
    float a0 = 0.f, a1 = 0.f, a2 = 0.f, a3 = 0.f, a4 = 0.f, a5 = 0.f, a6 = 0.f, a7 = 0.f;
    const float rs = 0.08838834764831845f;   // 1/sqrt(128)
    int beg = row_start[n], end = row_start[n + 1];
    int nit = (end - beg + 1) >> 1;
    int lbase = (h * 16 + sl) << 4;          // 32-bit offsets -> saddr-form loads
    for (int it = 0; it < nit; ++it) {
        int e0 = beg + 2 * it;
        int2 se0 = csr[e0];
        int2 se1 = csr[e0 + 1];          // may read 8B past last row's edges; in-ws, masked below
        int e = e0 + slot;
        bool valid = e < end;
        int2 se = slot ? se1 : se0;
        int sidx = se.x;
        float ea = __int_as_float(se.y);
        int koff = (sidx << 9) + lbase;
        uint4 kq = *(const uint4*)(kvpack + koff);
        uint4 vq = *(const uint4*)(kvpack + koff + 8);
        float p = q0 * bflo(kq.x) + q1 * bfhi(kq.x) + q2 * bflo(kq.y) + q3 * bfhi(kq.y) +
                  q4 * bflo(kq.z) + q5 * bfhi(kq.z) + q6 * bflo(kq.w) + q7 * bfhi(kq.w);
        p = wred16(p);
        float w = valid ? __expf((p + ea * qwe) * rs) : 0.f;
        s += w;
        sea = fmaf(w, ea, sea);
        a0 = fmaf(w, bflo(vq.x), a0);
        a1 = fmaf(w, bfhi(vq.x), a1);
        a2 = fmaf(w, bflo(vq.y), a2);
        a3 = fmaf(w, bfhi(vq.y), a3);
        a4 = fmaf(w, bflo(vq.z), a4);
        a5 = fmaf(w, bfhi(vq.z), a5);
        a6 = fmaf(w, bflo(vq.w), a6);
        a7 = fmaf(w, bfhi(vq.w), a7);
    }

    // merge the two edge slots (lane ^ 32): plain sums
    s += __shfl_xor(s, 32, 64);
    sea += __shfl_xor(sea, 32, 64);
    a0 += __shfl_xor(a0, 32, 64);
    a1 += __shfl_xor(a1, 32, 64);
    a2 += __shfl_xor(a2, 32, 64);
    a3 += __shfl_xor(a3, 32, 64);
    a4 += __shfl_xor(a4, 32, 64);
    a5 += __shfl_xor(a5, 32, 64);
    a6 += __shfl_xor(a6, 32, 64);
    a7 += __shfl_xor(a7, 32, 64);

    float inv = (s > 0.f) ? 1.f / s : 1.f;
    float sw = sea * inv;
    float o0 = a0 * inv + sw * wea.x;
    float o1 = a1 * inv + sw * wea.y;
    float o2 = a2 * inv + sw * wea.z;
    float o3 = a3 * inv + sw * wea.w;
    float o4 = a4 * inv + sw * web.x;
    float o5 = a5 * inv + sw * web.y;
    float o6 = a6 * inv + sw * web.z;
    float o7 = a7 * inv + sw * web.w;
    // head mean (h <-> h^1 is lane ^ 16)
    o0 = 0.5f * (o0 + __shfl_xor(o0, 16, 64));
    o1 = 0.5f * (o1 + __shfl_xor(o1, 16, 64));
    o2 = 0.5f * (o2 + __shfl_xor(o2, 16, 64));
    o3 = 0.5f * (o3 + __shfl_xor(o3, 16, 64));
    o4 = 0.5f * (o4 + __shfl_xor(o4, 16, 64));
    o5 = 0.5f * (o5 + __shfl_xor(o5, 16, 64));
    o6 = 0.5f * (o6 + __shfl_xor(o6, 16, 64));
    o7 = 0.5f * (o7 + __shfl_xor(o7, 16, 64));

    // + skip, ELU, residual, LN (dims dbase..dbase+7; 4x redundant across (slot,h))
    const float* skp = skipbuf + n * 128 + dbase;
    const float* xrp = xcur + n * 128 + dbase;
    float4 ska = *(const float4*)skp, skb = *(const float4*)(skp + 4);
    float4 xra = *(const float4*)xrp, xrb = *(const float4*)(xrp + 4);
    float y0 = o0 + ska.x, y1 = o1 + ska.y, y2 = o2 + ska.z, y3 = o3 + ska.w;
    float y4 = o4 + skb.x, y5 = o5 + skb.y, y6 = o6 + skb.z, y7 = o7 + skb.w;
    y0 = (y0 > 0.f) ? y0 : __expf(y0) - 1.f;
    y1 = (y1 > 0.f) ? y1 : __expf(y1) - 1.f;
    y2 = (y2 > 0.f) ? y2 : __expf(y2) - 1.f;
    y3 = (y3 > 0.f) ? y3 : __expf(y3) - 1.f;
    y4 = (y4 > 0.f) ? y4 : __expf(y4) - 1.f;
    y5 = (y5 > 0.f) ? y5 : __expf(y5) - 1.f;
    y6 = (y6 > 0.f) ? y6 : __expf(y6) - 1.f;
    y7 = (y7 > 0.f) ? y7 : __expf(y7) - 1.f;
    float p0 = xra.x + y0, p1 = xra.y + y1, p2 = xra.z + y2, p3 = xra.w + y3;
    float p4 = xrb.x + y4, p5 = xrb.y + y5, p6 = xrb.z + y6, p7 = xrb.w + y7;
    float mu = wred16(p0 + p1 + p2 + p3 + p4 + p5 + p6 + p7) * (1.f / 128.f);
    float c0 = p0 - mu, c1 = p1 - mu, c2 = p2 - mu, c3 = p3 - mu;
    float c4 = p4 - mu, c5 = p5 - mu, c6 = p6 - mu, c7 = p7 - mu;
    float var = wred16(c0 * c0 + c1 * c1 + c2 * c2 + c3 * c3 +
                       c4 * c4 + c5 * c5 + c6 * c6 + c7 * c7) * (1.f / 128.f);
    float r = rsqrtf(var + 1e-5f);
    if (lane < 16) {
        const float* gp = g + dbase;
        const float* bp = beta + dbase;
        float4 ga = *(const float4*)gp, gb = *(const float4*)(gp + 4);
        float4 ba = *(const float4*)bp, bb = *(const float4*)(bp + 4);
        float4 oa, ob;
        oa.x = c0 * r * ga.x + ba.x; oa.y = c1 * r * ga.y + ba.y;
        oa.z = c2 * r * ga.z + ba.z; oa.w = c3 * r * ga.w + ba.w;
        ob.x = c4 * r * gb.x + bb.x; ob.y = c5 * r * gb.y + bb.y;
        ob.z = c6 * r * gb.z + bb.z; ob.w = c7 * r * gb.w + bb.w;
        float* dp = dst + n * 128 + dbase;
        *(float4*)dp = oa;
        *(float4*)(dp + 4) = ob;
        if (xbout) {
            uint4 pk;
            pk.x = (unsigned)f2bf(oa.x) | ((unsigned)f2bf(oa.y) << 16);
            pk.y = (unsigned)f2bf(oa.z) | ((unsigned)f2bf(oa.w) << 16);
            pk.z = (unsigned)f2bf(ob.x) | ((unsigned)f2bf(ob.y) << 16);
            pk.w = (unsigned)f2bf(ob.z) | ((unsigned)f2bf(ob.w) << 16);
            *(uint4*)(xbout + n * 128 + dbase) = pk;
        }
    }
}

// ---------- launch ----------
extern "C" void kernel_launch(void* const* d_in, const int* in_sizes, int n_in,
                              void* d_out, int out_size, void* d_ws, size_t ws_size,
                              hipStream_t stream) {
    const float* x       = (const float*)d_in[0];
    const int*   ei      = (const int*)d_in[1];
    const float* eattr   = (const float*)d_in[2];
    const float* ln_in_g = (const float*)d_in[3];
    const float* ln_in_b = (const float*)d_in[4];
    const float* Wq = (const float*)d_in[5];
    const float* bq = (const float*)d_in[6];
    const float* Wk = (const float*)d_in[7];
    const float* bk = (const float*)d_in[8];
    const float* Wv = (const float*)d_in[9];
    const float* bv = (const float*)d_in[10];
    const float* We = (const float*)d_in[11];
    const float* Ws = (const float*)d_in[12];
    const float* bs = (const float*)d_in[13];
    const float* ln_g = (const float*)d_in[14];
    const float* ln_b = (const float*)d_in[15];
    float* out = (float*)d_out;

    char* p = (char*)d_ws;
    auto carve = [&](size_t bytes) {
        char* r = p;
        p += (bytes + 255) & ~(size_t)255;
        return (void*)r;
    };
    int*  cursor    = (int*)carve((size_t)NN * 4);
    int*  row_start = (int*)carve((size_t)(NN + 1) * 4);
    int*  bsums     = (int*)carve(1024);
    int2* csr       = (int2*)carve((size_t)NE * 8);
    unsigned short* WcatT = (unsigned short*)carve((size_t)NLAYERS * MCOLS * HIDS * 2);
    float* bcat     = (float*)carve((size_t)NLAYERS * MCOLS * 4);
    float* xcur     = (float*)carve((size_t)NN * HIDS * 4);
    unsigned short* qpack  = (unsigned short*)carve((size_t)NN * 256 * 2);
    unsigned short* kvpack = (unsigned short*)carve((size_t)NN * 512 * 2);
    float* skipbuf  = (float*)carve((size_t)NN * HIDS * 4);
    unsigned short* xb = (unsigned short*)carve((size_t)NN * HIDS * 2);

    const int NB_N = (NN + 255) / 256;       // 196
    const int NB_E = (NE + 255) / 256;       // 1954
    const int NODE_BLOCKS = (NN + 3) / 4;    // 12500

    // CSR build (edge_index layout: src = ei[0:E], tgt = ei[E:2E])
    hipMemsetAsync(cursor, 0, (size_t)NN * 4, stream);
    eatb_count<<<NB_E, 256, 0, stream>>>(ei + NE, cursor);
    eatb_blocksum<<<NB_N, 256, 0, stream>>>(cursor, bsums);
    eatb_scanb<<<1, 256, 0, stream>>>(bsums, NB_N);
    eatb_rowstart<<<NB_N, 256, 0, stream>>>(cursor, bsums, row_start);
    hipMemsetAsync(cursor, 0, (size_t)NN * 4, stream);
    eatb_scatter<<<NB_E, 256, 0, stream>>>(ei, ei + NE, eattr, row_start, cursor, csr);

    // pack weights (transposed bf16) + biases
    {
        int tot = NLAYERS * MCOLS * HIDS + NLAYERS * MCOLS;
        eatb_packw<<<(tot + 255) / 256, 256, 0, stream>>>(Wq, Wk, Wv, Ws, bq, bk, bv, bs, WcatT, bcat);
    }

    // input layernorm -> xcur (fp32) + xb (bf16)
    eatb_ln_in<<<NODE_BLOCKS, 256, 0, stream>>>(x, ln_in_g, ln_in_b, xcur, xb);

    // layers
    dim3 ggrid((NN + 127) / 128, MCOLS / 128);   // 391 x 7
    for (int l = 0; l < NLAYERS; ++l) {
        eatb_gemm<<<ggrid, 256, 0, stream>>>(xb, WcatT + (size_t)l * MCOLS * HIDS, bcat + (size_t)l * MCOLS,
                                             qpack, kvpack, skipbuf);
        float* dst = (l == NLAYERS - 1) ? out : xcur;
        unsigned short* xbo = (l == NLAYERS - 1) ? nullptr : xb;
        eatb_attn<<<NODE_BLOCKS, 256, 0, stream>>>(qpack, kvpack, skipbuf, csr, row_start,
                                                   We + (size_t)l * 256, ln_g + (size_t)l * 128,
                                                   ln_b + (size_t)l * 128, xcur, dst, xbo);
    }
    (void)in_sizes; (void)n_in; (void)out_size; (void)ws_size;
}

// Round 5
// 604.615 us; speedup vs baseline: 1.6655x; 1.0101x over previous
//
#include <hip/hip_runtime.h>
#include <math.h>

#define NN 50000
#define NE 500000
#define HIDS 128
#define MCOLS 896   // q(256) k(256) v(256) skip(128)
#define NLAYERS 3

typedef __attribute__((ext_vector_type(8))) short short8;
typedef __attribute__((ext_vector_type(4))) float floatx4;

#define STR 152     // LDS A/B row stride in shorts: 128+24 -> 304 B (16B-aligned, 2-way-free frag reads)

// ---------- helpers ----------
static __device__ __forceinline__ float bflo(unsigned u) { return __uint_as_float(u << 16); }
static __device__ __forceinline__ float bfhi(unsigned u) { return __uint_as_float(u & 0xffff0000u); }
static __device__ __forceinline__ unsigned short f2bf(float f) {
    unsigned u = __float_as_uint(f);
    u += 0x7fffu + ((u >> 16) & 1u);   // RNE
    return (unsigned short)(u >> 16);
}
// VALU-rate width-16 sum via DPP: xor1, xor2 (quad_perm), ror4, ror8 (row rotate).
// ~4x shorter latency chain than ds_swizzle-based __shfl_xor.
#define DPP_ADD(v, ctrl) \
    v += __int_as_float(__builtin_amdgcn_mov_dpp(__float_as_int(v), ctrl, 0xf, 0xf, true))
static __device__ __forceinline__ float wred16(float v) {
    DPP_ADD(v, 0xB1);    // quad_perm [1,0,3,2]  : lane ^ 1
    DPP_ADD(v, 0x4E);    // quad_perm [2,3,0,1]  : lane ^ 2
    DPP_ADD(v, 0x124);   // row_ror:4            : quad rotate
    DPP_ADD(v, 0x128);   // row_ror:8            : half-row rotate
    return v;
}
static __device__ __forceinline__ float wred64(float v) {
    v += __shfl_xor(v, 1, 64);
    v += __shfl_xor(v, 2, 64);
    v += __shfl_xor(v, 4, 64);
    v += __shfl_xor(v, 8, 64);
    v += __shfl_xor(v, 16, 64);
    v += __shfl_xor(v, 32, 64);
    return v;
}

// ---------- CSR build ----------
__global__ __launch_bounds__(256) void eatb_count(const int* __restrict__ tgt, int* __restrict__ cnt) {
    int e = blockIdx.x * 256 + threadIdx.x;
    if (e < NE) atomicAdd(&cnt[tgt[e]], 1);
}

__global__ __launch_bounds__(256) void eatb_blocksum(const int* __restrict__ cnt, int* __restrict__ bsums) {
    __shared__ int sm[256];
    int i = blockIdx.x * 256 + threadIdx.x;
    sm[threadIdx.x] = (i < NN) ? cnt[i] : 0;
    __syncthreads();
    for (int off = 128; off > 0; off >>= 1) {
        if (threadIdx.x < off) sm[threadIdx.x] += sm[threadIdx.x + off];
        __syncthreads();
    }
    if (threadIdx.x == 0) bsums[blockIdx.x] = sm[0];
}

__global__ __launch_bounds__(256) void eatb_scanb(int* __restrict__ bsums, int nb) {
    __shared__ int sm[256];
    int t = threadIdx.x;
    int v = (t < nb) ? bsums[t] : 0;
    sm[t] = v;
    __syncthreads();
    for (int off = 1; off < 256; off <<= 1) {
        int x = (t >= off) ? sm[t - off] : 0;
        __syncthreads();
        sm[t] += x;
        __syncthreads();
    }
    if (t < nb) bsums[t] = sm[t] - v;   // exclusive
}

__global__ __launch_bounds__(256) void eatb_rowstart(const int* __restrict__ cnt, const int* __restrict__ bsums,
                                                     int* __restrict__ row_start) {
    __shared__ int sm[256];
    int t = threadIdx.x;
    int i = blockIdx.x * 256 + t;
    int v = (i < NN) ? cnt[i] : 0;
    sm[t] = v;
    __syncthreads();
    for (int off = 1; off < 256; off <<= 1) {
        int x = (t >= off) ? sm[t - off] : 0;
        __syncthreads();
        sm[t] += x;
        __syncthreads();
    }
    int excl = sm[t] - v + bsums[blockIdx.x];
    if (i < NN) row_start[i] = excl;
    if (i == NN - 1) row_start[NN] = excl + v;
}

__global__ __launch_bounds__(256) void eatb_scatter(const int* __restrict__ src, const int* __restrict__ tgt,
                                                    const float* __restrict__ ea, const int* __restrict__ row_start,
                                                    int* __restrict__ cursor, int2* __restrict__ csr) {
    int e = blockIdx.x * 256 + threadIdx.x;
    if (e >= NE) return;
    int t = tgt[e];
    int pos = atomicAdd(&cursor[t], 1);
    int2 val;
    val.x = src[e];
    val.y = __float_as_int(ea[e]);
    csr[row_start[t] + pos] = val;
}

// ---------- pack transposed bf16 weights: WcatT[l][c=0..895][k=0..127] ----------
__global__ __launch_bounds__(256) void eatb_packw(const float* __restrict__ Wq, const float* __restrict__ Wk,
                                                  const float* __restrict__ Wv, const float* __restrict__ Ws,
                                                  const float* __restrict__ bq, const float* __restrict__ bk,
                                                  const float* __restrict__ bv, const float* __restrict__ bs,
                                                  unsigned short* __restrict__ Wt, float* __restrict__ bcat) {
    int idx = blockIdx.x * 256 + threadIdx.x;
    const int WTOT = NLAYERS * MCOLS * HIDS;
    if (idx < WTOT) {
        int l = idx / (MCOLS * HIDS);
        int rem = idx % (MCOLS * HIDS);
        int c = rem / HIDS, k = rem % HIDS;
        float v;
        if (c < 256)      v = Wq[(l * HIDS + k) * 256 + c];
        else if (c < 512) v = Wk[(l * HIDS + k) * 256 + c - 256];
        else if (c < 768) v = Wv[(l * HIDS + k) * 256 + c - 512];
        else              v = Ws[(l * HIDS + k) * 128 + c - 768];
        Wt[idx] = f2bf(v);
    } else {
        int i2 = idx - WTOT;
        if (i2 < NLAYERS * MCOLS) {
            int l = i2 / MCOLS, c = i2 % MCOLS;
            float v;
            if (c < 256)      v = bq[l * 256 + c];
            else if (c < 512) v = bk[l * 256 + c - 256];
            else if (c < 768) v = bv[l * 256 + c - 512];
            else              v = bs[l * 128 + c - 768];
            bcat[i2] = v;
        }
    }
}

// ---------- input layernorm (wave per node) -> fp32 xcur + bf16 xb ----------
__global__ __launch_bounds__(256) void eatb_ln_in(const float* __restrict__ x, const float* __restrict__ g,
                                                  const float* __restrict__ b, float* __restrict__ xout,
                                                  unsigned short* __restrict__ xb) {
    int wid = threadIdx.x >> 6, lane = threadIdx.x & 63;
    int n = blockIdx.x * 4 + wid;
    if (n >= NN) return;
    float2 v = *(const float2*)(x + (size_t)n * HIDS + 2 * lane);
    float mu = wred64(v.x + v.y) * (1.f / 128.f);
    float cx = v.x - mu, cy = v.y - mu;
    float var = wred64(cx * cx + cy * cy) * (1.f / 128.f);
    float r = rsqrtf(var + 1e-5f);
    float2 g2 = *(const float2*)(g + 2 * lane);
    float2 b2 = *(const float2*)(b + 2 * lane);
    float2 o;
    o.x = cx * r * g2.x + b2.x;
    o.y = cy * r * g2.y + b2.y;
    *(float2*)(xout + (size_t)n * HIDS + 2 * lane) = o;
    unsigned pk = (unsigned)f2bf(o.x) | ((unsigned)f2bf(o.y) << 16);
    *(unsigned*)(xb + (size_t)n * HIDS + 2 * lane) = pk;
}

// ---------- bf16 MFMA GEMM: [NN,128]bf16 @ [128,896]bf16 + bias, fused routing ----------
// qpack bf16 [NN][256] row-major
// kvpack bf16 [NN][head:2][sl:16][k 8 | v 8]  (32 B per (head,sl) granule, 1 KB per node)
// skipbuf fp32 [NN][128]
__global__ __launch_bounds__(256, 2) void eatb_gemm(const unsigned short* __restrict__ xb,
                                                    const unsigned short* __restrict__ Wt,
                                                    const float* __restrict__ bias,
                                                    unsigned short* __restrict__ qpack,
                                                    unsigned short* __restrict__ kvpack,
                                                    float* __restrict__ skipbuf) {
    __shared__ __align__(16) char smem[2 * 128 * STR * 2];   // 77824 B; C-stage (128*129*4=66048) unions in
    short* As = (short*)smem;            // [128][STR]
    short* Bs = As + 128 * STR;          // [128][STR]
    float* Cs = (float*)smem;            // [128][129]

    int tid = threadIdx.x;
    int r0 = blockIdx.x * 128;
    int c0 = blockIdx.y * 128;

    {   // stage A,B tiles: thread t loads 16B chunks; row=(t>>4)+16p, chunk=(t&15)*8 shorts
        int row = tid >> 4, ch = (tid & 15) * 8;
        #pragma unroll
        for (int p = 0; p < 8; ++p) {
            int r = row + p * 16;
            int gr = r0 + r;
            uint4 v = make_uint4(0, 0, 0, 0);
            if (gr < NN) v = *(const uint4*)(xb + (size_t)gr * HIDS + ch);
            *(uint4*)(As + r * STR + ch) = v;
        }
        #pragma unroll
        for (int p = 0; p < 8; ++p) {
            int r = row + p * 16;
            uint4 v = *(const uint4*)(Wt + (size_t)(c0 + r) * HIDS + ch);
            *(uint4*)(Bs + r * STR + ch) = v;
        }
    }
    __syncthreads();

    int wid = tid >> 6, lane = tid & 63;
    int fr = lane & 15;
    int kq = (lane >> 4) * 8;
    floatx4 acc[2][8] = {};
    #pragma unroll
    for (int ks = 0; ks < 4; ++ks) {
        int kof = ks * 32 + kq;
        short8 af0 = *(const short8*)(As + (wid * 32 + fr) * STR + kof);
        short8 af1 = *(const short8*)(As + (wid * 32 + 16 + fr) * STR + kof);
        short8 bf[8];
        #pragma unroll
        for (int n = 0; n < 8; ++n) bf[n] = *(const short8*)(Bs + (n * 16 + fr) * STR + kof);
        #pragma unroll
        for (int n = 0; n < 8; ++n) {
            acc[0][n] = __builtin_amdgcn_mfma_f32_16x16x32_bf16(af0, bf[n], acc[0][n], 0, 0, 0);
            acc[1][n] = __builtin_amdgcn_mfma_f32_16x16x32_bf16(af1, bf[n], acc[1][n], 0, 0, 0);
        }
    }
    __syncthreads();   // A/B reads done; reuse LDS for C staging
    #pragma unroll
    for (int mi = 0; mi < 2; ++mi)
        #pragma unroll
        for (int ni = 0; ni < 8; ++ni)
            #pragma unroll
            for (int rg = 0; rg < 4; ++rg) {
                int rr = wid * 32 + mi * 16 + (lane >> 4) * 4 + rg;
                int cc = ni * 16 + fr;
                Cs[rr * 129 + cc] = acc[mi][ni][rg];
            }
    __syncthreads();

    // routed stores: thread t: cols 4*(t&31).., rows (t>>5)+8p
    int cl = (tid & 31) * 4;
    int C = c0 + cl;
    float4 b4 = *(const float4*)(bias + C);
    for (int p = 0; p < 16; ++p) {
        int rr = (tid >> 5) + 8 * p;
        int gr = r0 + rr;
        if (gr >= NN) break;
        float v0 = Cs[rr * 129 + cl] + b4.x;
        float v1 = Cs[rr * 129 + cl + 1] + b4.y;
        float v2 = Cs[rr * 129 + cl + 2] + b4.z;
        float v3 = Cs[rr * 129 + cl + 3] + b4.w;
        if (C < 256) {
            ushort4 o;
            o.x = f2bf(v0); o.y = f2bf(v1); o.z = f2bf(v2); o.w = f2bf(v3);
            *(ushort4*)(qpack + (size_t)gr * 256 + C) = o;
        } else if (C < 768) {
            int u = C - 256;
            int part = u >> 7;        // 0:k h0, 1:k h1, 2:v h0, 3:v h1
            int h = part & 1, isv = part >> 1;
            int d0 = u & 127;         // dim base (multiple of 4)
            ushort4 o;
            o.x = f2bf(v0); o.y = f2bf(v1); o.z = f2bf(v2); o.w = f2bf(v3);
            size_t off = (size_t)gr * 512 + ((h * 16 + (d0 >> 3)) * 16) + isv * 8 + (d0 & 7);
            *(ushort4*)(kvpack + off) = o;
        } else {
            *(float4*)(skipbuf + (size_t)gr * 128 + (C - 768)) = make_float4(v0, v1, v2, v3);
        }
    }
}

// ---------- fused attention + epilogue: one wave per target node ----------
// lane map: slot = lane>>5 (edge slot), h = (lane>>4)&1, sl = lane&15 (dims sl*8..sl*8+7)
// No-max softmax (|alpha| << 88); 2x manual unroll = 4 edges in flight, two accumulator sets.
__global__ __launch_bounds__(256) void eatb_attn(const unsigned short* __restrict__ qpack,
                                                 const unsigned short* __restrict__ kvpack,
                                                 const float* __restrict__ skipbuf,
                                                 const int2* __restrict__ csr, const int* __restrict__ row_start,
                                                 const float* __restrict__ Wel, const float* __restrict__ g,
                                                 const float* __restrict__ beta, const float* __restrict__ xcur,
                                                 float* __restrict__ dst, unsigned short* __restrict__ xbout) {
    int wid = threadIdx.x >> 6;
    int lane = threadIdx.x & 63;
    int n = blockIdx.x * 4 + wid;
    if (n >= NN) return;
    int slot = lane >> 5;
    int h = (lane >> 4) & 1;
    int sl = lane & 15;
    int dbase = sl * 8;

    // q fragment (8 dims of head h), fp32
    uint4 qw = *(const uint4*)(qpack + n * 256 + h * 128 + dbase);
    float q0 = bflo(qw.x), q1 = bfhi(qw.x), q2 = bflo(qw.y), q3 = bfhi(qw.y);
    float q4 = bflo(qw.z), q5 = bfhi(qw.z), q6 = bflo(qw.w), q7 = bfhi(qw.w);
    const float* wep = Wel + h * 128 + dbase;
    float4 wea = *(const float4*)wep;
    float4 web = *(const float4*)(wep + 4);
    float qwe = wred16(q0 * wea.x + q1 * wea.y + q2 * wea.z + q3 * wea.w +
                       q4 * web.x + q5 * web.y + q6 * web.z + q7 * web.w);

    float sA = 0.f, seaA = 0.f, sB = 0.f, seaB = 0.f;
    float aA0 = 0.f, aA1 = 0.f, aA2 = 0.f, aA3 = 0.f, aA4 = 0.f, aA5 = 0.f, aA6 = 0.f, aA7 = 0.f;
    float aB0 = 0.f, aB1 = 0.f, aB2 = 0.f, aB3 = 0.f, aB4 = 0.f, aB5 = 0.f, aB6 = 0.f, aB7 = 0.f;
    const float rs = 0.08838834764831845f;   // 1/sqrt(128)
    int beg = row_start[n], end = row_start[n + 1];
    int deg = end - beg;
    int nit = (deg + 3) >> 2;
    int lbase = (h * 16 + sl) << 4;          // 32-bit offsets -> saddr-form loads
    for (int it = 0; it < nit; ++it) {
        int eA = beg + 4 * it + slot;
        int eB = eA + 2;
        bool vA = eA < end, vB = eB < end;
        int2 seA = csr[vA ? eA : beg];
        int2 seB = csr[vB ? eB : beg];
        int koA = (seA.x << 9) + lbase;
        int koB = (seB.x << 9) + lbase;
        uint4 kqA = *(const uint4*)(kvpack + koA);
        uint4 vqA = *(const uint4*)(kvpack + koA + 8);
        uint4 kqB = *(const uint4*)(kvpack + koB);
        uint4 vqB = *(const uint4*)(kvpack + koB + 8);
        float eaA = __int_as_float(seA.y);
        float eaB = __int_as_float(seB.y);
        float pA = q0 * bflo(kqA.x) + q1 * bfhi(kqA.x) + q2 * bflo(kqA.y) + q3 * bfhi(kqA.y) +
                   q4 * bflo(kqA.z) + q5 * bfhi(kqA.z) + q6 * bflo(kqA.w) + q7 * bfhi(kqA.w);
        float pB = q0 * bflo(kqB.x) + q1 * bfhi(kqB.x) + q2 * bflo(kqB.y) + q3 * bfhi(kqB.y) +
                   q4 * bflo(kqB.z) + q5 * bfhi(kqB.z) + q6 * bflo(kqB.w) + q7 * bfhi(kqB.w);
        pA = wred16(pA);
        pB = wred16(pB);
        float wA = vA ? __expf((pA + eaA * qwe) * rs) : 0.f;
        float wB = vB ? __expf((pB + eaB * qwe) * rs) : 0.f;
        sA += wA;
        sB += wB;
        seaA = fmaf(wA, eaA, seaA);
        seaB = fmaf(wB, eaB, seaB);
        aA0 = fmaf(wA, bflo(vqA.x), aA0);  aB0 = fmaf(wB, bflo(vqB.x), aB0);
        aA1 = fmaf(wA, bfhi(vqA.x), aA1);  aB1 = fmaf(wB, bfhi(vqB.x), aB1);
        aA2 = fmaf(wA, bflo(vqA.y), aA2);  aB2 = fmaf(wB, bflo(vqB.y), aB2);
        aA3 = fmaf(wA, bfhi(vqA.y), aA3);  aB3 = fmaf(wB, bfhi(vqB.y), aB3);
        aA4 = fmaf(wA, bflo(vqA.z), aA4);  aB4 = fmaf(wB, bflo(vqB.z), aB4);
        aA5 = fmaf(wA, bfhi(vqA.z), aA5);  aB5 = fmaf(wB, bfhi(vqB.z), aB5);
        aA6 = fmaf(wA, bflo(vqA.w), aA6);  aB6 = fmaf(wB, bflo(vqB.w), aB6);
        aA7 = fmaf(wA, bfhi(vqA.w), aA7);  aB7 = fmaf(wB, bfhi(vqB.w), aB7);
    }
    float s = sA + sB, sea = seaA + seaB;
    float a0 = aA0 + aB0, a1 = aA1 + aB1, a2 = aA2 + aB2, a3 = aA3 + aB3;
    float a4 = aA4 + aB4, a5 = aA5 + aB5, a6 = aA6 + aB6, a7 = aA7 + aB7;

    // merge the two edge slots (lane ^ 32): plain sums
    s += __shfl_xor(s, 32, 64);
    sea += __shfl_xor(sea, 32, 64);
    a0 += __shfl_xor(a0, 32, 64);
    a1 += __shfl_xor(a1, 32, 64);
    a2 += __shfl_xor(a2, 32, 64);
    a3 += __shfl_xor(a3, 32, 64);
    a4 += __shfl_xor(a4, 32, 64);
    a5 += __shfl_xor(a5, 32, 64);
    a6 += __shfl_xor(a6, 32, 64);
    a7 += __shfl_xor(a7, 32, 64);

    float inv = (s > 0.f) ? 1.f / s : 1.f;
    float sw = sea * inv;
    float o0 = a0 * inv + sw * wea.x;
    float o1 = a1 * inv + sw * wea.y;
    float o2 = a2 * inv + sw * wea.z;
    float o3 = a3 * inv + sw * wea.w;
    float o4 = a4 * inv + sw * web.x;
    float o5 = a5 * inv + sw * web.y;
    float o6 = a6 * inv + sw * web.z;
    float o7 = a7 * inv + sw * web.w;
    // head mean (h <-> h^1 is lane ^ 16)
    o0 = 0.5f * (o0 + __shfl_xor(o0, 16, 64));
    o1 = 0.5f * (o1 + __shfl_xor(o1, 16, 64));
    o2 = 0.5f * (o2 + __shfl_xor(o2, 16, 64));
    o3 = 0.5f * (o3 + __shfl_xor(o3, 16, 64));
    o4 = 0.5f * (o4 + __shfl_xor(o4, 16, 64));
    o5 = 0.5f * (o5 + __shfl_xor(o5, 16, 64));
    o6 = 0.5f * (o6 + __shfl_xor(o6, 16, 64));
    o7 = 0.5f * (o7 + __shfl_xor(o7, 16, 64));

    // + skip, ELU, residual, LN (dims dbase..dbase+7; 4x redundant across (slot,h))
    const float* skp = skipbuf + n * 128 + dbase;
    const float* xrp = xcur + n * 128 + dbase;
    float4 ska = *(const float4*)skp, skb = *(const float4*)(skp + 4);
    float4 xra = *(const float4*)xrp, xrb = *(const float4*)(xrp + 4);
    float y0 = o0 + ska.x, y1 = o1 + ska.y, y2 = o2 + ska.z, y3 = o3 + ska.w;
    float y4 = o4 + skb.x, y5 = o5 + skb.y, y6 = o6 + skb.z, y7 = o7 + skb.w;
    y0 = (y0 > 0.f) ? y0 : __expf(y0) - 1.f;
    y1 = (y1 > 0.f) ? y1 : __expf(y1) - 1.f;
    y2 = (y2 > 0.f) ? y2 : __expf(y2) - 1.f;
    y3 = (y3 > 0.f) ? y3 : __expf(y3) - 1.f;
    y4 = (y4 > 0.f) ? y4 : __expf(y4) - 1.f;
    y5 = (y5 > 0.f) ? y5 : __expf(y5) - 1.f;
    y6 = (y6 > 0.f) ? y6 : __expf(y6) - 1.f;
    y7 = (y7 > 0.f) ? y7 : __expf(y7) - 1.f;
    float p0 = xra.x + y0, p1 = xra.y + y1, p2 = xra.z + y2, p3 = xra.w + y3;
    float p4 = xrb.x + y4, p5 = xrb.y + y5, p6 = xrb.z + y6, p7 = xrb.w + y7;
    float mu = wred16(p0 + p1 + p2 + p3 + p4 + p5 + p6 + p7) * (1.f / 128.f);
    float c0 = p0 - mu, c1 = p1 - mu, c2 = p2 - mu, c3 = p3 - mu;
    float c4 = p4 - mu, c5 = p5 - mu, c6 = p6 - mu, c7 = p7 - mu;
    float var = wred16(c0 * c0 + c1 * c1 + c2 * c2 + c3 * c3 +
                       c4 * c4 + c5 * c5 + c6 * c6 + c7 * c7) * (1.f / 128.f);
    float r = rsqrtf(var + 1e-5f);
    if (lane < 16) {
        const float* gp = g + dbase;
        const float* bp = beta + dbase;
        float4 ga = *(const float4*)gp, gb = *(const float4*)(gp + 4);
        float4 ba = *(const float4*)bp, bb = *(const float4*)(bp + 4);
        float4 oa, ob;
        oa.x = c0 * r * ga.x + ba.x; oa.y = c1 * r * ga.y + ba.y;
        oa.z = c2 * r * ga.z + ba.z; oa.w = c3 * r * ga.w + ba.w;
        ob.x = c4 * r * gb.x + bb.x; ob.y = c5 * r * gb.y + bb.y;
        ob.z = c6 * r * gb.z + bb.z; ob.w = c7 * r * gb.w + bb.w;
        float* dp = dst + n * 128 + dbase;
        *(float4*)dp = oa;
        *(float4*)(dp + 4) = ob;
        if (xbout) {
            uint4 pk;
            pk.x = (unsigned)f2bf(oa.x) | ((unsigned)f2bf(oa.y) << 16);
            pk.y = (unsigned)f2bf(oa.z) | ((unsigned)f2bf(oa.w) << 16);
            pk.z = (unsigned)f2bf(ob.x) | ((unsigned)f2bf(ob.y) << 16);
            pk.w = (unsigned)f2bf(ob.z) | ((unsigned)f2bf(ob.w) << 16);
            *(uint4*)(xbout + n * 128 + dbase) = pk;
        }
    }
}

// ---------- launch ----------
extern "C" void kernel_launch(void* const* d_in, const int* in_sizes, int n_in,
                              void* d_out, int out_size, void* d_ws, size_t ws_size,
                              hipStream_t stream) {
    const float* x       = (const float*)d_in[0];
    const int*   ei      = (const int*)d_in[1];
    const float* eattr   = (const float*)d_in[2];
    const float* ln_in_g = (const float*)d_in[3];
    const float* ln_in_b = (const float*)d_in[4];
    const float* Wq = (const float*)d_in[5];
    const float* bq = (const float*)d_in[6];
    const float* Wk = (const float*)d_in[7];
    const float* bk = (const float*)d_in[8];
    const float* Wv = (const float*)d_in[9];
    const float* bv = (const float*)d_in[10];
    const float* We = (const float*)d_in[11];
    const float* Ws = (const float*)d_in[12];
    const float* bs = (const float*)d_in[13];
    const float* ln_g = (const float*)d_in[14];
    const float* ln_b = (const float*)d_in[15];
    float* out = (float*)d_out;

    char* p = (char*)d_ws;
    auto carve = [&](size_t bytes) {
        char* r = p;
        p += (bytes + 255) & ~(size_t)255;
        return (void*)r;
    };
    int*  cursor    = (int*)carve((size_t)NN * 4);
    int*  row_start = (int*)carve((size_t)(NN + 1) * 4);
    int*  bsums     = (int*)carve(1024);
    int2* csr       = (int2*)carve((size_t)NE * 8);
    unsigned short* WcatT = (unsigned short*)carve((size_t)NLAYERS * MCOLS * HIDS * 2);
    float* bcat     = (float*)carve((size_t)NLAYERS * MCOLS * 4);
    float* xcur     = (float*)carve((size_t)NN * HIDS * 4);
    unsigned short* qpack  = (unsigned short*)carve((size_t)NN * 256 * 2);
    unsigned short* kvpack = (unsigned short*)carve((size_t)NN * 512 * 2);
    float* skipbuf  = (float*)carve((size_t)NN * HIDS * 4);
    unsigned short* xb = (unsigned short*)carve((size_t)NN * HIDS * 2);

    const int NB_N = (NN + 255) / 256;       // 196
    const int NB_E = (NE + 255) / 256;       // 1954
    const int NODE_BLOCKS = (NN + 3) / 4;    // 12500

    // CSR build (edge_index layout: src = ei[0:E], tgt = ei[E:2E])
    hipMemsetAsync(cursor, 0, (size_t)NN * 4, stream);
    eatb_count<<<NB_E, 256, 0, stream>>>(ei + NE, cursor);
    eatb_blocksum<<<NB_N, 256, 0, stream>>>(cursor, bsums);
    eatb_scanb<<<1, 256, 0, stream>>>(bsums, NB_N);
    eatb_rowstart<<<NB_N, 256, 0, stream>>>(cursor, bsums, row_start);
    hipMemsetAsync(cursor, 0, (size_t)NN * 4, stream);
    eatb_scatter<<<NB_E, 256, 0, stream>>>(ei, ei + NE, eattr, row_start, cursor, csr);

    // pack weights (transposed bf16) + biases
    {
        int tot = NLAYERS * MCOLS * HIDS + NLAYERS * MCOLS;
        eatb_packw<<<(tot + 255) / 256, 256, 0, stream>>>(Wq, Wk, Wv, Ws, bq, bk, bv, bs, WcatT, bcat);
    }

    // input layernorm -> xcur (fp32) + xb (bf16)
    eatb_ln_in<<<NODE_BLOCKS, 256, 0, stream>>>(x, ln_in_g, ln_in_b, xcur, xb);

    // layers
    dim3 ggrid((NN + 127) / 128, MCOLS / 128);   // 391 x 7
    for (int l = 0; l < NLAYERS; ++l) {
        eatb_gemm<<<ggrid, 256, 0, stream>>>(xb, WcatT + (size_t)l * MCOLS * HIDS, bcat + (size_t)l * MCOLS,
                                             qpack, kvpack, skipbuf);
        float* dst = (l == NLAYERS - 1) ? out : xcur;
        unsigned short* xbo = (l == NLAYERS - 1) ? nullptr : xb;
        eatb_attn<<<NODE_BLOCKS, 256, 0, stream>>>(qpack, kvpack, skipbuf, csr, row_start,
                                                   We + (size_t)l * 256, ln_g + (size_t)l * 128,
                                                   ln_b + (size_t)l * 128, xcur, dst, xbo);
    }
    (void)in_sizes; (void)n_in; (void)out_size; (void)ws_size;
}

// Round 6
// 576.152 us; speedup vs baseline: 1.7478x; 1.0494x over previous
//
#include <hip/hip_runtime.h>
#include <math.h>

#define NN 50000
#define NE 500000
#define HIDS 128
#define MCOLS 896   // q(256) k(256) v(256) skip(128)
#define NLAYERS 3

typedef __attribute__((ext_vector_type(8))) short short8;
typedef __attribute__((ext_vector_type(4))) float floatx4;
typedef _Float16 half8v __attribute__((ext_vector_type(8)));

#define STR 152     // LDS A/B row stride in shorts: 128+24 -> 304 B (16B-aligned, 2-way-free frag reads)

// ---------- helpers ----------
static __device__ __forceinline__ unsigned short f2bf(float f) {
    unsigned u = __float_as_uint(f);
    u += 0x7fffu + ((u >> 16) & 1u);   // RNE
    return (unsigned short)(u >> 16);
}
static __device__ __forceinline__ unsigned short f2h(float f) {
    union { _Float16 h; unsigned short u; } c;
    c.h = (_Float16)f;
    return c.u;
}
// VALU-rate width-16 sum via DPP: xor1, xor2 (quad_perm), ror4, ror8 (row rotate).
#define DPP_ADD(v, ctrl) \
    v += __int_as_float(__builtin_amdgcn_mov_dpp(__float_as_int(v), ctrl, 0xf, 0xf, true))
static __device__ __forceinline__ float wred16(float v) {
    DPP_ADD(v, 0xB1);    // quad_perm [1,0,3,2]  : lane ^ 1
    DPP_ADD(v, 0x4E);    // quad_perm [2,3,0,1]  : lane ^ 2
    DPP_ADD(v, 0x124);   // row_ror:4            : quad rotate
    DPP_ADD(v, 0x128);   // row_ror:8            : half-row rotate
    return v;
}
static __device__ __forceinline__ float wred64(float v) {
    v += __shfl_xor(v, 1, 64);
    v += __shfl_xor(v, 2, 64);
    v += __shfl_xor(v, 4, 64);
    v += __shfl_xor(v, 8, 64);
    v += __shfl_xor(v, 16, 64);
    v += __shfl_xor(v, 32, 64);
    return v;
}

// ---------- CSR build ----------
__global__ __launch_bounds__(256) void eatb_count(const int* __restrict__ tgt, int* __restrict__ cnt) {
    int e = blockIdx.x * 256 + threadIdx.x;
    if (e < NE) atomicAdd(&cnt[tgt[e]], 1);
}

__global__ __launch_bounds__(256) void eatb_blocksum(const int* __restrict__ cnt, int* __restrict__ bsums) {
    __shared__ int sm[256];
    int i = blockIdx.x * 256 + threadIdx.x;
    sm[threadIdx.x] = (i < NN) ? cnt[i] : 0;
    __syncthreads();
    for (int off = 128; off > 0; off >>= 1) {
        if (threadIdx.x < off) sm[threadIdx.x] += sm[threadIdx.x + off];
        __syncthreads();
    }
    if (threadIdx.x == 0) bsums[blockIdx.x] = sm[0];
}

__global__ __launch_bounds__(256) void eatb_scanb(int* __restrict__ bsums, int nb) {
    __shared__ int sm[256];
    int t = threadIdx.x;
    int v = (t < nb) ? bsums[t] : 0;
    sm[t] = v;
    __syncthreads();
    for (int off = 1; off < 256; off <<= 1) {
        int x = (t >= off) ? sm[t - off] : 0;
        __syncthreads();
        sm[t] += x;
        __syncthreads();
    }
    if (t < nb) bsums[t] = sm[t] - v;   // exclusive
}

__global__ __launch_bounds__(256) void eatb_rowstart(const int* __restrict__ cnt, const int* __restrict__ bsums,
                                                     int* __restrict__ row_start) {
    __shared__ int sm[256];
    int t = threadIdx.x;
    int i = blockIdx.x * 256 + t;
    int v = (i < NN) ? cnt[i] : 0;
    sm[t] = v;
    __syncthreads();
    for (int off = 1; off < 256; off <<= 1) {
        int x = (t >= off) ? sm[t - off] : 0;
        __syncthreads();
        sm[t] += x;
        __syncthreads();
    }
    int excl = sm[t] - v + bsums[blockIdx.x];
    if (i < NN) row_start[i] = excl;
    if (i == NN - 1) row_start[NN] = excl + v;
}

__global__ __launch_bounds__(256) void eatb_scatter(const int* __restrict__ src, const int* __restrict__ tgt,
                                                    const float* __restrict__ ea, const int* __restrict__ row_start,
                                                    int* __restrict__ cursor, int2* __restrict__ csr) {
    int e = blockIdx.x * 256 + threadIdx.x;
    if (e >= NE) return;
    int t = tgt[e];
    int pos = atomicAdd(&cursor[t], 1);
    int2 val;
    val.x = src[e];
    val.y = __float_as_int(ea[e]);
    csr[row_start[t] + pos] = val;
}

// ---------- pack transposed bf16 weights: WcatT[l][c=0..895][k=0..127] ----------
__global__ __launch_bounds__(256) void eatb_packw(const float* __restrict__ Wq, const float* __restrict__ Wk,
                                                  const float* __restrict__ Wv, const float* __restrict__ Ws,
                                                  const float* __restrict__ bq, const float* __restrict__ bk,
                                                  const float* __restrict__ bv, const float* __restrict__ bs,
                                                  unsigned short* __restrict__ Wt, float* __restrict__ bcat) {
    int idx = blockIdx.x * 256 + threadIdx.x;
    const int WTOT = NLAYERS * MCOLS * HIDS;
    if (idx < WTOT) {
        int l = idx / (MCOLS * HIDS);
        int rem = idx % (MCOLS * HIDS);
        int c = rem / HIDS, k = rem % HIDS;
        float v;
        if (c < 256)      v = Wq[(l * HIDS + k) * 256 + c];
        else if (c < 512) v = Wk[(l * HIDS + k) * 256 + c - 256];
        else if (c < 768) v = Wv[(l * HIDS + k) * 256 + c - 512];
        else              v = Ws[(l * HIDS + k) * 128 + c - 768];
        Wt[idx] = f2bf(v);
    } else {
        int i2 = idx - WTOT;
        if (i2 < NLAYERS * MCOLS) {
            int l = i2 / MCOLS, c = i2 % MCOLS;
            float v;
            if (c < 256)      v = bq[l * 256 + c];
            else if (c < 512) v = bk[l * 256 + c - 256];
            else if (c < 768) v = bv[l * 256 + c - 512];
            else              v = bs[l * 128 + c - 768];
            bcat[i2] = v;
        }
    }
}

// ---------- input layernorm (wave per node) -> fp32 xcur + bf16 xb ----------
__global__ __launch_bounds__(256) void eatb_ln_in(const float* __restrict__ x, const float* __restrict__ g,
                                                  const float* __restrict__ b, float* __restrict__ xout,
                                                  unsigned short* __restrict__ xb) {
    int wid = threadIdx.x >> 6, lane = threadIdx.x & 63;
    int n = blockIdx.x * 4 + wid;
    if (n >= NN) return;
    float2 v = *(const float2*)(x + (size_t)n * HIDS + 2 * lane);
    float mu = wred64(v.x + v.y) * (1.f / 128.f);
    float cx = v.x - mu, cy = v.y - mu;
    float var = wred64(cx * cx + cy * cy) * (1.f / 128.f);
    float r = rsqrtf(var + 1e-5f);
    float2 g2 = *(const float2*)(g + 2 * lane);
    float2 b2 = *(const float2*)(b + 2 * lane);
    float2 o;
    o.x = cx * r * g2.x + b2.x;
    o.y = cy * r * g2.y + b2.y;
    *(float2*)(xout + (size_t)n * HIDS + 2 * lane) = o;
    unsigned pk = (unsigned)f2bf(o.x) | ((unsigned)f2bf(o.y) << 16);
    *(unsigned*)(xb + (size_t)n * HIDS + 2 * lane) = pk;
}

// ---------- bf16 MFMA GEMM: [NN,128]bf16 @ [128,896]bf16 + bias, fused routing ----------
// 512 threads (8 waves): wave w -> rows w*16..w*16+15, all 128 cols; 2 blocks/CU (16 waves).
// qpack f16 [NN][256] row-major; kvpack f16 [NN][head:2][sl:16][k 8 | v 8]; skipbuf fp32 [NN][128]
__global__ __launch_bounds__(512, 1) void eatb_gemm(const unsigned short* __restrict__ xb,
                                                    const unsigned short* __restrict__ Wt,
                                                    const float* __restrict__ bias,
                                                    unsigned short* __restrict__ qpack,
                                                    unsigned short* __restrict__ kvpack,
                                                    float* __restrict__ skipbuf) {
    __shared__ __align__(16) char smem[2 * 128 * STR * 2];   // 77824 B; C-stage (128*129*4=66048) unions in
    short* As = (short*)smem;            // [128][STR]
    short* Bs = As + 128 * STR;          // [128][STR]
    float* Cs = (float*)smem;            // [128][129]

    int tid = threadIdx.x;
    int r0 = blockIdx.x * 128;
    int c0 = blockIdx.y * 128;

    {   // stage A,B tiles: thread t: row=(t>>4)+32p, chunk=(t&15)*8 shorts
        int row = tid >> 4, ch = (tid & 15) * 8;
        #pragma unroll
        for (int p = 0; p < 4; ++p) {
            int r = row + p * 32;
            int gr = r0 + r;
            uint4 v = make_uint4(0, 0, 0, 0);
            if (gr < NN) v = *(const uint4*)(xb + (size_t)gr * HIDS + ch);
            *(uint4*)(As + r * STR + ch) = v;
        }
        #pragma unroll
        for (int p = 0; p < 4; ++p) {
            int r = row + p * 32;
            uint4 v = *(const uint4*)(Wt + (size_t)(c0 + r) * HIDS + ch);
            *(uint4*)(Bs + r * STR + ch) = v;
        }
    }
    __syncthreads();

    int wid = tid >> 6, lane = tid & 63;
    int fr = lane & 15;
    int kq = (lane >> 4) * 8;
    floatx4 acc[8] = {};
    #pragma unroll
    for (int ks = 0; ks < 4; ++ks) {
        int kof = ks * 32 + kq;
        short8 af = *(const short8*)(As + (wid * 16 + fr) * STR + kof);
        #pragma unroll
        for (int n = 0; n < 8; ++n) {
            short8 bf = *(const short8*)(Bs + (n * 16 + fr) * STR + kof);
            acc[n] = __builtin_amdgcn_mfma_f32_16x16x32_bf16(af, bf, acc[n], 0, 0, 0);
        }
    }
    __syncthreads();   // A/B reads done; reuse LDS for C staging
    #pragma unroll
    for (int ni = 0; ni < 8; ++ni)
        #pragma unroll
        for (int rg = 0; rg < 4; ++rg) {
            int rr = wid * 16 + (lane >> 4) * 4 + rg;
            Cs[rr * 129 + ni * 16 + fr] = acc[ni][rg];
        }
    __syncthreads();

    // routed stores: thread t: cols 4*(t&31).., rows (t>>5)+16p
    int cl = (tid & 31) * 4;
    int C = c0 + cl;
    float4 b4 = *(const float4*)(bias + C);
    #pragma unroll
    for (int p = 0; p < 8; ++p) {
        int rr = (tid >> 5) + 16 * p;
        int gr = r0 + rr;
        if (gr >= NN) break;
        float v0 = Cs[rr * 129 + cl] + b4.x;
        float v1 = Cs[rr * 129 + cl + 1] + b4.y;
        float v2 = Cs[rr * 129 + cl + 2] + b4.z;
        float v3 = Cs[rr * 129 + cl + 3] + b4.w;
        if (C < 256) {
            ushort4 o;
            o.x = f2h(v0); o.y = f2h(v1); o.z = f2h(v2); o.w = f2h(v3);
            *(ushort4*)(qpack + (size_t)gr * 256 + C) = o;
        } else if (C < 768) {
            int u = C - 256;
            int part = u >> 7;        // 0:k h0, 1:k h1, 2:v h0, 3:v h1
            int h = part & 1, isv = part >> 1;
            int d0 = u & 127;         // dim base (multiple of 4)
            ushort4 o;
            o.x = f2h(v0); o.y = f2h(v1); o.z = f2h(v2); o.w = f2h(v3);
            size_t off = (size_t)gr * 512 + ((h * 16 + (d0 >> 3)) * 16) + isv * 8 + (d0 & 7);
            *(ushort4*)(kvpack + off) = o;
        } else {
            *(float4*)(skipbuf + (size_t)gr * 128 + (C - 768)) = make_float4(v0, v1, v2, v3);
        }
    }
}

// ---------- fused attention + epilogue: one wave per target node ----------
// lane map: slot = lane>>5 (edge slot), h = (lane>>4)&1, sl = lane&15 (dims sl*8..sl*8+7)
// f16 tables -> v_fma_mix accumulate (no unpack ops); q pre-scaled by 1/sqrt(128).
__global__ __launch_bounds__(256) void eatb_attn(const unsigned short* __restrict__ qpack,
                                                 const unsigned short* __restrict__ kvpack,
                                                 const float* __restrict__ skipbuf,
                                                 const int2* __restrict__ csr, const int* __restrict__ row_start,
                                                 const float* __restrict__ Wel, const float* __restrict__ g,
                                                 const float* __restrict__ beta, const float* __restrict__ xcur,
                                                 float* __restrict__ dst, unsigned short* __restrict__ xbout) {
    int wid = threadIdx.x >> 6;
    int lane = threadIdx.x & 63;
    int n = blockIdx.x * 4 + wid;
    if (n >= NN) return;
    int slot = lane >> 5;
    int h = (lane >> 4) & 1;
    int sl = lane & 15;
    int dbase = sl * 8;

    const float rs = 0.08838834764831845f;   // 1/sqrt(128), folded into q
    const _Float16* qh16 = (const _Float16*)qpack;
    const _Float16* kvh = (const _Float16*)kvpack;

    half8v qh = *(const half8v*)(qh16 + n * 256 + h * 128 + dbase);
    float q0 = (float)qh[0] * rs, q1 = (float)qh[1] * rs, q2 = (float)qh[2] * rs, q3 = (float)qh[3] * rs;
    float q4 = (float)qh[4] * rs, q5 = (float)qh[5] * rs, q6 = (float)qh[6] * rs, q7 = (float)qh[7] * rs;
    const float* wep = Wel + h * 128 + dbase;
    float4 wea = *(const float4*)wep;
    float4 web = *(const float4*)(wep + 4);
    float qwe = wred16(q0 * wea.x + q1 * wea.y + q2 * wea.z + q3 * wea.w +
                       q4 * web.x + q5 * web.y + q6 * web.z + q7 * web.w);

    float sA = 0.f, seaA = 0.f, sB = 0.f, seaB = 0.f;
    float aA0 = 0.f, aA1 = 0.f, aA2 = 0.f, aA3 = 0.f, aA4 = 0.f, aA5 = 0.f, aA6 = 0.f, aA7 = 0.f;
    float aB0 = 0.f, aB1 = 0.f, aB2 = 0.f, aB3 = 0.f, aB4 = 0.f, aB5 = 0.f, aB6 = 0.f, aB7 = 0.f;
    int beg = row_start[n], end = row_start[n + 1];
    int nit = (end - beg + 3) >> 2;
    int lbase = (h * 16 + sl) << 4;          // 32-bit offsets -> saddr-form loads
    for (int it = 0; it < nit; ++it) {
        int eA = beg + 4 * it + slot;
        int eB = eA + 2;
        bool vA = eA < end, vB = eB < end;
        int2 seA = csr[vA ? eA : beg];
        int2 seB = csr[vB ? eB : beg];
        int koA = (seA.x << 9) + lbase;
        int koB = (seB.x << 9) + lbase;
        half8v kqA = *(const half8v*)(kvh + koA);
        half8v vqA = *(const half8v*)(kvh + koA + 8);
        half8v kqB = *(const half8v*)(kvh + koB);
        half8v vqB = *(const half8v*)(kvh + koB + 8);
        float eaA = __int_as_float(seA.y);
        float eaB = __int_as_float(seB.y);
        float pA = q0 * (float)kqA[0] + q1 * (float)kqA[1] + q2 * (float)kqA[2] + q3 * (float)kqA[3] +
                   q4 * (float)kqA[4] + q5 * (float)kqA[5] + q6 * (float)kqA[6] + q7 * (float)kqA[7];
        float pB = q0 * (float)kqB[0] + q1 * (float)kqB[1] + q2 * (float)kqB[2] + q3 * (float)kqB[3] +
                   q4 * (float)kqB[4] + q5 * (float)kqB[5] + q6 * (float)kqB[6] + q7 * (float)kqB[7];
        pA = wred16(pA);
        pB = wred16(pB);
        float wA = vA ? __expf(pA + eaA * qwe) : 0.f;
        float wB = vB ? __expf(pB + eaB * qwe) : 0.f;
        sA += wA;
        sB += wB;
        seaA = fmaf(wA, eaA, seaA);
        seaB = fmaf(wB, eaB, seaB);
        aA0 = fmaf(wA, (float)vqA[0], aA0);  aB0 = fmaf(wB, (float)vqB[0], aB0);
        aA1 = fmaf(wA, (float)vqA[1], aA1);  aB1 = fmaf(wB, (float)vqB[1], aB1);
        aA2 = fmaf(wA, (float)vqA[2], aA2);  aB2 = fmaf(wB, (float)vqB[2], aB2);
        aA3 = fmaf(wA, (float)vqA[3], aA3);  aB3 = fmaf(wB, (float)vqB[3], aB3);
        aA4 = fmaf(wA, (float)vqA[4], aA4);  aB4 = fmaf(wB, (float)vqB[4], aB4);
        aA5 = fmaf(wA, (float)vqA[5], aA5);  aB5 = fmaf(wB, (float)vqB[5], aB5);
        aA6 = fmaf(wA, (float)vqA[6], aA6);  aB6 = fmaf(wB, (float)vqB[6], aB6);
        aA7 = fmaf(wA, (float)vqA[7], aA7);  aB7 = fmaf(wB, (float)vqB[7], aB7);
    }
    float s = sA + sB, sea = seaA + seaB;
    float a0 = aA0 + aB0, a1 = aA1 + aB1, a2 = aA2 + aB2, a3 = aA3 + aB3;
    float a4 = aA4 + aB4, a5 = aA5 + aB5, a6 = aA6 + aB6, a7 = aA7 + aB7;

    // merge the two edge slots (lane ^ 32): plain sums
    s += __shfl_xor(s, 32, 64);
    sea += __shfl_xor(sea, 32, 64);
    a0 += __shfl_xor(a0, 32, 64);
    a1 += __shfl_xor(a1, 32, 64);
    a2 += __shfl_xor(a2, 32, 64);
    a3 += __shfl_xor(a3, 32, 64);
    a4 += __shfl_xor(a4, 32, 64);
    a5 += __shfl_xor(a5, 32, 64);
    a6 += __shfl_xor(a6, 32, 64);
    a7 += __shfl_xor(a7, 32, 64);

    float inv = (s > 0.f) ? 1.f / s : 1.f;
    float sw = sea * inv;
    float o0 = a0 * inv + sw * wea.x;
    float o1 = a1 * inv + sw * wea.y;
    float o2 = a2 * inv + sw * wea.z;
    float o3 = a3 * inv + sw * wea.w;
    float o4 = a4 * inv + sw * web.x;
    float o5 = a5 * inv + sw * web.y;
    float o6 = a6 * inv + sw * web.z;
    float o7 = a7 * inv + sw * web.w;
    // head mean (h <-> h^1 is lane ^ 16)
    o0 = 0.5f * (o0 + __shfl_xor(o0, 16, 64));
    o1 = 0.5f * (o1 + __shfl_xor(o1, 16, 64));
    o2 = 0.5f * (o2 + __shfl_xor(o2, 16, 64));
    o3 = 0.5f * (o3 + __shfl_xor(o3, 16, 64));
    o4 = 0.5f * (o4 + __shfl_xor(o4, 16, 64));
    o5 = 0.5f * (o5 + __shfl_xor(o5, 16, 64));
    o6 = 0.5f * (o6 + __shfl_xor(o6, 16, 64));
    o7 = 0.5f * (o7 + __shfl_xor(o7, 16, 64));

    // + skip, ELU, residual, LN (dims dbase..dbase+7; 4x redundant across (slot,h))
    const float* skp = skipbuf + n * 128 + dbase;
    const float* xrp = xcur + n * 128 + dbase;
    float4 ska = *(const float4*)skp, skb = *(const float4*)(skp + 4);
    float4 xra = *(const float4*)xrp, xrb = *(const float4*)(xrp + 4);
    float y0 = o0 + ska.x, y1 = o1 + ska.y, y2 = o2 + ska.z, y3 = o3 + ska.w;
    float y4 = o4 + skb.x, y5 = o5 + skb.y, y6 = o6 + skb.z, y7 = o7 + skb.w;
    y0 = (y0 > 0.f) ? y0 : __expf(y0) - 1.f;
    y1 = (y1 > 0.f) ? y1 : __expf(y1) - 1.f;
    y2 = (y2 > 0.f) ? y2 : __expf(y2) - 1.f;
    y3 = (y3 > 0.f) ? y3 : __expf(y3) - 1.f;
    y4 = (y4 > 0.f) ? y4 : __expf(y4) - 1.f;
    y5 = (y5 > 0.f) ? y5 : __expf(y5) - 1.f;
    y6 = (y6 > 0.f) ? y6 : __expf(y6) - 1.f;
    y7 = (y7 > 0.f) ? y7 : __expf(y7) - 1.f;
    float p0 = xra.x + y0, p1 = xra.y + y1, p2 = xra.z + y2, p3 = xra.w + y3;
    float p4 = xrb.x + y4, p5 = xrb.y + y5, p6 = xrb.z + y6, p7 = xrb.w + y7;
    float mu = wred16(p0 + p1 + p2 + p3 + p4 + p5 + p6 + p7) * (1.f / 128.f);
    float c0 = p0 - mu, c1 = p1 - mu, c2 = p2 - mu, c3 = p3 - mu;
    float c4 = p4 - mu, c5 = p5 - mu, c6 = p6 - mu, c7 = p7 - mu;
    float var = wred16(c0 * c0 + c1 * c1 + c2 * c2 + c3 * c3 +
                       c4 * c4 + c5 * c5 + c6 * c6 + c7 * c7) * (1.f / 128.f);
    float r = rsqrtf(var + 1e-5f);
    if (lane < 16) {
        const float* gp = g + dbase;
        const float* bp = beta + dbase;
        float4 ga = *(const float4*)gp, gb = *(const float4*)(gp + 4);
        float4 ba = *(const float4*)bp, bb = *(const float4*)(bp + 4);
        float4 oa, ob;
        oa.x = c0 * r * ga.x + ba.x; oa.y = c1 * r * ga.y + ba.y;
        oa.z = c2 * r * ga.z + ba.z; oa.w = c3 * r * ga.w + ba.w;
        ob.x = c4 * r * gb.x + bb.x; ob.y = c5 * r * gb.y + bb.y;
        ob.z = c6 * r * gb.z + bb.z; ob.w = c7 * r * gb.w + bb.w;
        float* dp = dst + n * 128 + dbase;
        *(float4*)dp = oa;
        *(float4*)(dp + 4) = ob;
        if (xbout) {
            uint4 pk;
            pk.x = (unsigned)f2bf(oa.x) | ((unsigned)f2bf(oa.y) << 16);
            pk.y = (unsigned)f2bf(oa.z) | ((unsigned)f2bf(oa.w) << 16);
            pk.z = (unsigned)f2bf(ob.x) | ((unsigned)f2bf(ob.y) << 16);
            pk.w = (unsigned)f2bf(ob.z) | ((unsigned)f2bf(ob.w) << 16);
            *(uint4*)(xbout + n * 128 + dbase) = pk;
        }
    }
}

// ---------- launch ----------
extern "C" void kernel_launch(void* const* d_in, const int* in_sizes, int n_in,
                              void* d_out, int out_size, void* d_ws, size_t ws_size,
                              hipStream_t stream) {
    const float* x       = (const float*)d_in[0];
    const int*   ei      = (const int*)d_in[1];
    const float* eattr   = (const float*)d_in[2];
    const float* ln_in_g = (const float*)d_in[3];
    const float* ln_in_b = (const float*)d_in[4];
    const float* Wq = (const float*)d_in[5];
    const float* bq = (const float*)d_in[6];
    const float* Wk = (const float*)d_in[7];
    const float* bk = (const float*)d_in[8];
    const float* Wv = (const float*)d_in[9];
    const float* bv = (const float*)d_in[10];
    const float* We = (const float*)d_in[11];
    const float* Ws = (const float*)d_in[12];
    const float* bs = (const float*)d_in[13];
    const float* ln_g = (const float*)d_in[14];
    const float* ln_b = (const float*)d_in[15];
    float* out = (float*)d_out;

    char* p = (char*)d_ws;
    auto carve = [&](size_t bytes) {
        char* r = p;
        p += (bytes + 255) & ~(size_t)255;
        return (void*)r;
    };
    int*  cursor    = (int*)carve((size_t)NN * 4);
    int*  row_start = (int*)carve((size_t)(NN + 1) * 4);
    int*  bsums     = (int*)carve(1024);
    int2* csr       = (int2*)carve((size_t)NE * 8);
    unsigned short* WcatT = (unsigned short*)carve((size_t)NLAYERS * MCOLS * HIDS * 2);
    float* bcat     = (float*)carve((size_t)NLAYERS * MCOLS * 4);
    float* xcur     = (float*)carve((size_t)NN * HIDS * 4);
    unsigned short* qpack  = (unsigned short*)carve((size_t)NN * 256 * 2);
    unsigned short* kvpack = (unsigned short*)carve((size_t)NN * 512 * 2);
    float* skipbuf  = (float*)carve((size_t)NN * HIDS * 4);
    unsigned short* xb = (unsigned short*)carve((size_t)NN * HIDS * 2);

    const int NB_N = (NN + 255) / 256;       // 196
    const int NB_E = (NE + 255) / 256;       // 1954
    const int NODE_BLOCKS = (NN + 3) / 4;    // 12500

    // CSR build (edge_index layout: src = ei[0:E], tgt = ei[E:2E])
    hipMemsetAsync(cursor, 0, (size_t)NN * 4, stream);
    eatb_count<<<NB_E, 256, 0, stream>>>(ei + NE, cursor);
    eatb_blocksum<<<NB_N, 256, 0, stream>>>(cursor, bsums);
    eatb_scanb<<<1, 256, 0, stream>>>(bsums, NB_N);
    eatb_rowstart<<<NB_N, 256, 0, stream>>>(cursor, bsums, row_start);
    hipMemsetAsync(cursor, 0, (size_t)NN * 4, stream);
    eatb_scatter<<<NB_E, 256, 0, stream>>>(ei, ei + NE, eattr, row_start, cursor, csr);

    // pack weights (transposed bf16) + biases
    {
        int tot = NLAYERS * MCOLS * HIDS + NLAYERS * MCOLS;
        eatb_packw<<<(tot + 255) / 256, 256, 0, stream>>>(Wq, Wk, Wv, Ws, bq, bk, bv, bs, WcatT, bcat);
    }

    // input layernorm -> xcur (fp32) + xb (bf16)
    eatb_ln_in<<<NODE_BLOCKS, 256, 0, stream>>>(x, ln_in_g, ln_in_b, xcur, xb);

    // layers
    dim3 ggrid((NN + 127) / 128, MCOLS / 128);   // 391 x 7
    for (int l = 0; l < NLAYERS; ++l) {
        eatb_gemm<<<ggrid, 512, 0, stream>>>(xb, WcatT + (size_t)l * MCOLS * HIDS, bcat + (size_t)l * MCOLS,
                                             qpack, kvpack, skipbuf);
        float* dst = (l == NLAYERS - 1) ? out : xcur;
        unsigned short* xbo = (l == NLAYERS - 1) ? nullptr : xb;
        eatb_attn<<<NODE_BLOCKS, 256, 0, stream>>>(qpack, kvpack, skipbuf, csr, row_start,
                                                   We + (size_t)l * 256, ln_g + (size_t)l * 128,
                                                   ln_b + (size_t)l * 128, xcur, dst, xbo);
    }
    (void)in_sizes; (void)n_in; (void)out_size; (void)ws_size;
}